// Round 9
// baseline (1109.402 us; speedup 1.0000x reference)
//
#include <hip/hip_runtime.h>
#include <hip/hip_bf16.h>

// ---------------- constants ----------------
#define Nn_   120000
#define F_    256
#define H_    256
#define L_    64
#define EMP_  1000000
#define E_    200000
#define P0_   60000
#define P1_   80000
#define P2_   100000
#define PROXW 0.3f

typedef __attribute__((ext_vector_type(8))) short bf16x8;
typedef __attribute__((ext_vector_type(4))) float f32x4;

__device__ inline float bf2f(unsigned short u) {
    union { unsigned int i; float f; } x; x.i = ((unsigned int)u) << 16; return x.f;
}
__device__ inline unsigned short f2bf(float f) {
    union { float f; unsigned int i; } x; x.f = f;
    unsigned int r = x.i + 0x7fffu + ((x.i >> 16) & 1u);
    return (unsigned short)(r >> 16);
}
__device__ inline float tanh_fast(float x) {
    float e = __expf(2.0f * x);
    return 1.0f - 2.0f * __builtin_amdgcn_rcpf(e + 1.0f);
}
__device__ inline float sigmoid_fast(float z) {
    return __builtin_amdgcn_rcpf(1.0f + __expf(-z));
}
__device__ inline int lds_off(int row, int s) {
    return row * 64 + ((s ^ ((row >> 1) & 3)) << 4);
}
__device__ inline void gload_lds16(const void* g, void* l) {
    __builtin_amdgcn_global_load_lds((const __attribute__((address_space(1))) void*)g,
                                     (__attribute__((address_space(3))) void*)l, 16, 0, 0);
}
__device__ inline void unpk8(uint4 u, float* o) {
    o[0] = bf2f(u.x & 0xffff); o[1] = bf2f(u.x >> 16);
    o[2] = bf2f(u.y & 0xffff); o[3] = bf2f(u.y >> 16);
    o[4] = bf2f(u.z & 0xffff); o[5] = bf2f(u.z >> 16);
    o[6] = bf2f(u.w & 0xffff); o[7] = bf2f(u.w >> 16);
}
// mean & max of two packed bf16 pairs; max needs no re-rounding
__device__ inline void meanmax_u(unsigned int ua, unsigned int ub,
                                 unsigned int& um, unsigned int& ux) {
    float alo = __uint_as_float(ua << 16);
    float ahi = __uint_as_float(ua & 0xffff0000u);
    float blo = __uint_as_float(ub << 16);
    float bhi = __uint_as_float(ub & 0xffff0000u);
    um = (unsigned int)f2bf((alo + blo) * 0.5f) |
         ((unsigned int)f2bf((ahi + bhi) * 0.5f) << 16);
    ux = (__float_as_uint(fmaxf(alo, blo)) >> 16) |
         (__float_as_uint(fmaxf(ahi, bhi)) & 0xffff0000u);
}
__device__ inline float dot2_u(unsigned int ug, unsigned int ub) {
    float gl = __uint_as_float(ug << 16);
    float gh = __uint_as_float(ug & 0xffff0000u);
    float bl = __uint_as_float(ub << 16);
    float bh = __uint_as_float(ub & 0xffff0000u);
    return fmaf(gl, bl, gh * bh);
}

// ---------------- CSR build ----------------
__global__ void k_count(const int* __restrict__ dst, int* __restrict__ cnt, int n) {
    int e = blockIdx.x * 256 + threadIdx.x;
    if (e < n) atomicAdd(&cnt[dst[e]], 1);
}
__global__ void k_block_reduce(const int* __restrict__ cnt, int* __restrict__ bsum, int n) {
    __shared__ int s[256];
    int i = blockIdx.x * 256 + threadIdx.x;
    s[threadIdx.x] = (i < n) ? cnt[i] : 0;
    __syncthreads();
    for (int o = 128; o > 0; o >>= 1) {
        if (threadIdx.x < o) s[threadIdx.x] += s[threadIdx.x + o];
        __syncthreads();
    }
    if (threadIdx.x == 0) bsum[blockIdx.x] = s[0];
}
__global__ void k_scan_bsum(int* bsum, int nb) {
    if (threadIdx.x == 0 && blockIdx.x == 0) {
        int acc = 0;
        for (int i = 0; i < nb; i++) { int v = bsum[i]; bsum[i] = acc; acc += v; }
    }
}
__global__ void k_scan_final(const int* __restrict__ cnt, const int* __restrict__ bsum,
                             int* __restrict__ rowp, int n, int etot) {
    __shared__ int s[256];
    int tid = threadIdx.x;
    int i = blockIdx.x * 256 + tid;
    int v = (i < n) ? cnt[i] : 0;
    s[tid] = v;
    __syncthreads();
    for (int o = 1; o < 256; o <<= 1) {
        int t = 0;
        if (tid >= o) t = s[tid - o];
        __syncthreads();
        s[tid] += t;
        __syncthreads();
    }
    if (i < n) rowp[i] = bsum[blockIdx.x] + s[tid] - v;
    if (i == 0 && blockIdx.x == 0) rowp[n] = etot;
}
__global__ void k_fill(const int* __restrict__ src, const int* __restrict__ dst,
                       const int* __restrict__ rowp, int* __restrict__ fill,
                       int* __restrict__ csr, int n) {
    int e = blockIdx.x * 256 + threadIdx.x;
    if (e < n) {
        int d = dst[e];
        int p = atomicAdd(&fill[d], 1);
        csr[rowp[d] + p] = src[e];
    }
}
__global__ void k_dinv(const int* __restrict__ cnt, float* __restrict__ dinv, int n) {
    int i = blockIdx.x * 256 + threadIdx.x;
    if (i < n) dinv[i] = rsqrtf((float)cnt[i] + 1.0f);
}

// ---------------- small f32 tiled GEMM (256^3 precomputes only) ----------------
#define TM 64
#define TN 64
#define TK 16
template <bool TRANSB>
__global__ void gemm_tiled(const float* __restrict__ A, const float* __restrict__ B,
                           float* __restrict__ C, int M, int K, int N) {
    __shared__ float As[TK][TM + 4];
    __shared__ float Bs[TK][TN + 4];
    int tid = threadIdx.x;
    int tx = tid & 15, ty = tid >> 4;
    int row0 = blockIdx.y * TM, col0 = blockIdx.x * TN;
    int lr = tid >> 2, lc4 = (tid & 3) * 4;
    float acc[4][4] = {};
    for (int k0 = 0; k0 < K; k0 += TK) {
        {
            int gr = row0 + lr;
            float4 v = make_float4(0.f, 0.f, 0.f, 0.f);
            if (gr < M) v = *(const float4*)(A + (size_t)gr * K + k0 + lc4);
            As[lc4 + 0][lr] = v.x; As[lc4 + 1][lr] = v.y;
            As[lc4 + 2][lr] = v.z; As[lc4 + 3][lr] = v.w;
        }
        {
            int n = tid & 63, kk0 = tid >> 6;
#pragma unroll
            for (int p = 0; p < 4; p++) {
                int kk = kk0 + p * 4;
                if (TRANSB) Bs[kk][n] = B[(size_t)(col0 + n) * K + k0 + kk];
                else        Bs[kk][n] = B[(size_t)(k0 + kk) * N + col0 + n];
            }
        }
        __syncthreads();
#pragma unroll
        for (int kk = 0; kk < TK; kk++) {
            float4 a = *(const float4*)&As[kk][ty * 4];
            float4 b = *(const float4*)&Bs[kk][tx * 4];
            float av[4] = {a.x, a.y, a.z, a.w};
            float bv[4] = {b.x, b.y, b.z, b.w};
#pragma unroll
            for (int i = 0; i < 4; i++)
#pragma unroll
                for (int j = 0; j < 4; j++) acc[i][j] += av[i] * bv[j];
        }
        __syncthreads();
    }
#pragma unroll
    for (int i = 0; i < 4; i++) {
        int r = row0 + ty * 4 + i;
        if (r >= M) continue;
#pragma unroll
        for (int j = 0; j < 4; j++) C[(size_t)r * N + col0 + tx * 4 + j] = acc[i][j];
    }
}

// ---------------- conversions ----------------
__global__ void k_cvt(const float* __restrict__ in, unsigned short* __restrict__ out, int n4) {
    int i = blockIdx.x * 256 + threadIdx.x;
    if (i >= n4) return;
    float4 v = ((const float4*)in)[i];
    ushort4 o;
    o.x = f2bf(v.x); o.y = f2bf(v.y); o.z = f2bf(v.z); o.w = f2bf(v.w);
    ((ushort4*)out)[i] = o;
}

// Pack Wsrc[512][256] f32 -> fragment layout chunks (see mfma_edge B-read mapping)
__device__ inline void packBF_task(const float* __restrict__ Wsrc,
                                   unsigned short* __restrict__ P, int blk) {
    int t = blk * 256 + threadIdx.x;
    int c = t >> 6, l = t & 63;
    int os = c >> 5, half = (c >> 4) & 1, colb = c & 15;
    int col = (colb << 4) + (l & 15);
    int k = (half << 8) + (os << 5) + ((l >> 4) << 3);
    bf16x8 v;
#pragma unroll
    for (int j = 0; j < 8; ++j) v[j] = (short)f2bf(Wsrc[(size_t)(k + j) * 256 + col]);
    *(bf16x8*)(P + (size_t)t * 8) = v;
}

// consolidated weight prep #1 (input-only deps): 1153 blocks
__global__ void k_prep1(const float* __restrict__ gc1W, const float* __restrict__ gc2W,
                        const float* __restrict__ msdrW, const float* __restrict__ wlin,
                        const float* __restrict__ blin, const float* __restrict__ mlw1,
                        const float* __restrict__ msw1,
                        unsigned short* __restrict__ gc1Wt, unsigned short* __restrict__ gc2Wt,
                        unsigned short* __restrict__ msdrWt, unsigned short* __restrict__ symb,
                        float* __restrict__ sumb, unsigned short* __restrict__ mlPk,
                        unsigned short* __restrict__ msPk) {
    __shared__ float s[256];
    int b = blockIdx.x, tid = threadIdx.x;
    if (b < 256) {
        int c = b;
        for (int r = tid; r < 256; r += 256) gc1Wt[c * 256 + r] = f2bf(gc1W[(size_t)r * 256 + c]);
    } else if (b < 512) {
        int c = b - 256;
        for (int r = tid; r < 256; r += 256) gc2Wt[c * 256 + r] = f2bf(gc2W[(size_t)r * 256 + c]);
    } else if (b < 768) {
        int c = b - 512;
        if (tid < 64) msdrWt[c * 64 + tid] = f2bf(msdrW[(size_t)tid * 256 + c]);
    } else if (b < 1024) {
        int r = b - 768, c = tid;
        symb[r * 256 + c] = f2bf(0.5f * (wlin[r * 256 + c] + wlin[c * 256 + r]));
    } else if (b == 1024) {
        s[tid] = blin[tid];
        __syncthreads();
        for (int o = 128; o > 0; o >>= 1) {
            if (tid < o) s[tid] += s[tid + o];
            __syncthreads();
        }
        if (tid == 0) sumb[0] = s[0];
    } else if (b < 1089) {
        packBF_task(mlw1, mlPk, b - 1025);
    } else {
        packBF_task(msw1, msPk, b - 1089);
    }
}
// consolidated weight prep #2 (after gemm_tiled): 768 blocks
__global__ void k_prep2(const float* __restrict__ Mqk, const float* __restrict__ linW,
                        const float* __restrict__ W2w, unsigned short* __restrict__ MqkT,
                        unsigned short* __restrict__ Bt) {
    int b = blockIdx.x, tid = threadIdx.x;
    if (b < 256) {
        int c = b;
        for (int r = tid; r < 256; r += 256) MqkT[c * 256 + r] = f2bf(Mqk[(size_t)r * 256 + c]);
    } else {
        int idx = (b - 256) * 256 + tid;
        int n = idx >> 9, k = idx & 511;
        float v = (k < 256) ? linW[(size_t)k * 256 + n] : W2w[(size_t)(k - 256) * 256 + n];
        Bt[idx] = f2bf(v);
    }
}

// ---------------- GCN aggregation: one wave per node, 1-deep neighbor prefetch ----------------
__global__ __launch_bounds__(256)
void k_agg_bf(const unsigned short* __restrict__ xw, const int* __restrict__ rowp,
              const int* __restrict__ csr, const float* __restrict__ dinv,
              const float* __restrict__ bias, unsigned short* __restrict__ out) {
    int w = threadIdx.x >> 6, lane = threadIdx.x & 63;
    int v = blockIdx.x * 4 + w;
    if (v >= Nn_) return;
    const uint2* x64 = (const uint2*)xw;
    float a0 = 0.f, a1 = 0.f, a2 = 0.f, a3 = 0.f;
    int beg = rowp[v], end = rowp[v + 1];
    uint2 un = make_uint2(0, 0); float dn = 0.f;
    if (beg < end) {
        int s0 = csr[beg];
        dn = dinv[s0];
        un = x64[(size_t)s0 * 64 + lane];
    }
    for (int p = beg; p < end; ++p) {
        uint2 uc = un; float dc = dn;
        if (p + 1 < end) {
            int s1 = csr[p + 1];
            dn = dinv[s1];
            un = x64[(size_t)s1 * 64 + lane];
        }
        a0 += bf2f(uc.x & 0xffff) * dc;
        a1 += bf2f(uc.x >> 16) * dc;
        a2 += bf2f(uc.y & 0xffff) * dc;
        a3 += bf2f(uc.y >> 16) * dc;
    }
    float dv = dinv[v];
    uint2 us = x64[(size_t)v * 64 + lane];
    a0 = a0 * dv + bf2f(us.x & 0xffff) * dv * dv;
    a1 = a1 * dv + bf2f(us.x >> 16) * dv * dv;
    a2 = a2 * dv + bf2f(us.y & 0xffff) * dv * dv;
    a3 = a3 * dv + bf2f(us.y >> 16) * dv * dv;
    int c0 = lane * 4;
    float4 bv = *(const float4*)(bias + c0);
    uint2 ov;
    ov.x = (unsigned int)f2bf(tanh_fast(a0 + bv.x)) |
           ((unsigned int)f2bf(tanh_fast(a1 + bv.y)) << 16);
    ov.y = (unsigned int)f2bf(tanh_fast(a2 + bv.z)) |
           ((unsigned int)f2bf(tanh_fast(a3 + bv.w)) << 16);
    ((uint2*)out)[(size_t)v * 64 + lane] = ov;
}

// ---------------- MFMA GEMM, dbuf LDS + raw barriers + counted vmcnt ----------------
template <bool BIAS, bool TANH>
__global__ __launch_bounds__(256)
void mfma_gemm(const unsigned short* __restrict__ A0, const unsigned short* __restrict__ A1,
               int Ksplit, int K, const unsigned short* __restrict__ Bt,
               const float* __restrict__ bias, unsigned short* __restrict__ Cb, int M) {
    __shared__ char lds[2][16384];
    int tid = threadIdx.x, lane = tid & 63, w = tid >> 6;
    int row0 = blockIdx.y * 128, col0 = blockIdx.x * 128;
    int wr = w >> 1, wc = w & 1;
    f32x4 acc[4][4] = {};
    int nk = K >> 5;

    auto stage = [&](int ks, int buf) {
        int k0 = ks << 5;
        #pragma unroll
        for (int j = 0; j < 4; ++j) {
            int ins = w + (j << 2);
            int lrow = ((ins & 7) << 4) + (lane >> 2);
            int p = lane & 3;
            int slog = p ^ ((lrow >> 1) & 3);
            char* ldst = lds[buf] + ((ins & 7) << 10) + ((ins >= 8) ? 8192 : 0);
            const unsigned short* src;
            if (ins < 8) {
                int grow = row0 + lrow;
                if (grow >= M) grow = M - 1;
                const unsigned short* Asrc; int kk, pitch;
                if (k0 < Ksplit) { Asrc = A0; kk = k0; pitch = Ksplit; }
                else             { Asrc = A1; kk = k0 - Ksplit; pitch = K - Ksplit; }
                src = Asrc + (size_t)grow * pitch + kk + (slog << 3);
            } else {
                int grow = col0 + lrow;
                src = Bt + (size_t)grow * K + k0 + (slog << 3);
            }
            gload_lds16(src, ldst);
        }
    };

    stage(0, 0);
    for (int ks = 0; ks < nk; ++ks) {
        int cur = ks & 1;
        if (ks + 1 < nk) {
            stage(ks + 1, cur ^ 1);
            asm volatile("s_waitcnt vmcnt(4)" ::: "memory");
        } else {
            asm volatile("s_waitcnt vmcnt(0)" ::: "memory");
        }
        __builtin_amdgcn_s_barrier();
        __builtin_amdgcn_sched_barrier(0);
        int s = lane >> 4, r16 = lane & 15;
        bf16x8 a[4], b[4];
        #pragma unroll
        for (int m = 0; m < 4; ++m) a[m] = *(const bf16x8*)(lds[cur] + lds_off(wr * 64 + m * 16 + r16, s));
        #pragma unroll
        for (int n = 0; n < 4; ++n) b[n] = *(const bf16x8*)(lds[cur] + 8192 + lds_off(wc * 64 + n * 16 + r16, s));
        __builtin_amdgcn_s_setprio(1);
        #pragma unroll
        for (int m = 0; m < 4; ++m)
            #pragma unroll
            for (int n = 0; n < 4; ++n)
                acc[m][n] = __builtin_amdgcn_mfma_f32_16x16x32_bf16(a[m], b[n], acc[m][n], 0, 0, 0);
        __builtin_amdgcn_s_setprio(0);
        __builtin_amdgcn_s_barrier();
        __builtin_amdgcn_sched_barrier(0);
    }
    int q = lane >> 4, r16 = lane & 15;
    float bv[4];
    #pragma unroll
    for (int n = 0; n < 4; ++n) bv[n] = BIAS ? bias[col0 + wc * 64 + n * 16 + r16] : 0.f;
    #pragma unroll
    for (int m = 0; m < 4; ++m) {
        #pragma unroll
        for (int i = 0; i < 4; ++i) {
            int row = row0 + wr * 64 + m * 16 + q * 4 + i;
            if (row >= M) continue;
            #pragma unroll
            for (int n = 0; n < 4; ++n) {
                int col = col0 + wc * 64 + n * 16 + r16;
                float v = acc[m][n][i];
                if (BIAS) v += bv[n];
                if (TANH) v = tanh_fast(v);
                Cb[(size_t)row * 256 + col] = f2bf(v);
            }
        }
    }
}

// ---------------- attention u: 16 lanes/node, online softmax ----------------
__global__ __launch_bounds__(256)
void k_attn_u2(const unsigned short* __restrict__ emb, const unsigned short* __restrict__ t,
               const float* __restrict__ p0, const float* __restrict__ p1,
               const float* __restrict__ p2, unsigned short* __restrict__ u) {
    int tid = threadIdx.x;
    int g = tid >> 4, l = tid & 15;
    int n = blockIdx.x * 16 + g;
    size_t eoff = (size_t)n * 256 + l * 16;
    const uint4* e16 = (const uint4*)(emb + eoff);
    uint4* u16 = (uint4*)(u + eoff);
    uint4 eb0 = e16[0], eb1 = e16[1];
    if (n >= P2_) { u16[0] = eb0; u16[1] = eb1; return; }
    float tv[16], ev[16];
    {
        const uint4* t16 = (const uint4*)(t + eoff);
        unpk8(t16[0], tv); unpk8(t16[1], tv + 8);
        unpk8(eb0, ev); unpk8(eb1, ev + 8);
    }
    float m = -3.0e38f, den = 0.f, o[16];
    #pragma unroll
    for (int i = 0; i < 16; i++) o[i] = 0.f;
    auto accum = [&](const float* sv) {
        float dt = 0.f;
        #pragma unroll
        for (int i = 0; i < 16; i++) dt += tv[i] * sv[i];
        dt += __shfl_xor(dt, 1);
        dt += __shfl_xor(dt, 2);
        dt += __shfl_xor(dt, 4);
        dt += __shfl_xor(dt, 8);
        float lg = dt * 0.0625f;
        float mn = fmaxf(m, lg);
        float s0 = __expf(m - mn), s1 = __expf(lg - mn);
        den = den * s0 + s1;
        #pragma unroll
        for (int i = 0; i < 16; i++) o[i] = o[i] * s0 + s1 * sv[i];
        m = mn;
    };
    auto accum_f32 = [&](const float* base) {
        float sv[16];
        const float4* b4 = (const float4*)(base + eoff);
        #pragma unroll
        for (int i = 0; i < 4; i++) {
            float4 q = b4[i];
            sv[4 * i] = q.x; sv[4 * i + 1] = q.y; sv[4 * i + 2] = q.z; sv[4 * i + 3] = q.w;
        }
        accum(sv);
    };
    if (n < P0_)      { accum_f32(p0); accum_f32(p1); accum_f32(p2); }
    else if (n < P1_) { accum_f32(p1); accum_f32(p2); }
    else              { accum_f32(p2); }
    accum(ev);
    float inv = __builtin_amdgcn_rcpf(den);
    unsigned short h[16];
    #pragma unroll
    for (int i = 0; i < 16; i++) h[i] = f2bf(o[i] * inv);
    uint4 r0, r1;
    r0.x = h[0] | ((unsigned int)h[1] << 16);  r0.y = h[2] | ((unsigned int)h[3] << 16);
    r0.z = h[4] | ((unsigned int)h[5] << 16);  r0.w = h[6] | ((unsigned int)h[7] << 16);
    r1.x = h[8] | ((unsigned int)h[9] << 16);  r1.y = h[10] | ((unsigned int)h[11] << 16);
    r1.z = h[12] | ((unsigned int)h[13] << 16); r1.w = h[14] | ((unsigned int)h[15] << 16);
    u16[0] = r0; u16[1] = r1;
}

// ---------------- merged edge MLPs v6: both MLPs per gather, B-loads before prefetch ----------------
__global__ __launch_bounds__(256)
void mfma_edge6(const unsigned short* __restrict__ emb2, const unsigned short* __restrict__ rtab,
                const unsigned short* __restrict__ gsrc,
                const int* __restrict__ es, const int* __restrict__ ed,
                const unsigned short* __restrict__ PkMl, const unsigned short* __restrict__ PkMs,
                const float* __restrict__ b1ml, const float* __restrict__ w2ml,
                const float* __restrict__ b1ms, const float* __restrict__ w2ms,
                const float* __restrict__ sumb,
                float* __restrict__ apml, float* __restrict__ apms,
                float* __restrict__ mlsc) {
    __shared__ char lds[16384];   // ml-mean | ml-max | ms-mean | ms-max (4KB each)
    __shared__ float redml[64], redms[64];
    int tid = threadIdx.x, lane = tid & 63, w = tid >> 6;
    int e0 = blockIdx.x * 64;
    int arow = tid >> 2, p = tid & 3;
    int ia = es[e0 + arow], ib = ed[e0 + arow];
    const unsigned short* ea = emb2 + (size_t)ia * 256;
    const unsigned short* eb = emb2 + (size_t)ib * 256;
    const unsigned short* ra = rtab + (size_t)ia * 256;
    const unsigned short* rb = rtab + (size_t)ib * 256;
    const unsigned short* rg = gsrc + (size_t)ia * 256;
    int slog = p ^ ((arow >> 1) & 3);
    int co = slog << 3;
    int abase = arow * 64 + (p << 4);
    if (tid < 64) { redml[tid] = 0.f; redms[tid] = 0.f; }
    f32x4 accml[4][4] = {}, accms[4][4] = {};
    float simacc = 0.f;
    const bf16x8* BL = (const bf16x8*)PkMl;
    const bf16x8* BS = (const bf16x8*)PkMs;
    // prologue: prefetch step-0 rows (5 x uint4)
    uint4 pea = *(const uint4*)(ea + co);
    uint4 peb = *(const uint4*)(eb + co);
    uint4 pra = *(const uint4*)(ra + co);
    uint4 prb = *(const uint4*)(rb + co);
    uint4 pg  = *(const uint4*)(rg + co);
    for (int os = 0; os < 8; ++os) {
        // converts + swizzled ds_writes (auto-waits on prefetched regs)
        {
            unsigned int m0, x0, m1, x1, m2, x2, m3, x3;
            meanmax_u(pea.x, peb.x, m0, x0); meanmax_u(pea.y, peb.y, m1, x1);
            meanmax_u(pea.z, peb.z, m2, x2); meanmax_u(pea.w, peb.w, m3, x3);
            *(uint4*)(lds + abase) = make_uint4(m0, m1, m2, m3);
            *(uint4*)(lds + 4096 + abase) = make_uint4(x0, x1, x2, x3);
            simacc += dot2_u(pg.x, peb.x) + dot2_u(pg.y, peb.y) +
                      dot2_u(pg.z, peb.z) + dot2_u(pg.w, peb.w);
            meanmax_u(pra.x, prb.x, m0, x0); meanmax_u(pra.y, prb.y, m1, x1);
            meanmax_u(pra.z, prb.z, m2, x2); meanmax_u(pra.w, prb.w, m3, x3);
            *(uint4*)(lds + 8192 + abase) = make_uint4(m0, m1, m2, m3);
            *(uint4*)(lds + 12288 + abase) = make_uint4(x0, x1, x2, x3);
        }
        // ALL B-fragment loads for this step BEFORE the A-prefetch (vmcnt is FIFO:
        // anything issued after the prefetch would force the prefetch to drain)
        bf16x8 bml0[4], bml1[4], bms0[4], bms1[4];
        #pragma unroll
        for (int n2 = 0; n2 < 4; ++n2) {
            int c0i = (os << 5) + (w << 2) + n2;
            bml0[n2] = BL[(size_t)c0i * 64 + lane];
            bml1[n2] = BL[(size_t)(c0i + 16) * 64 + lane];
            bms0[n2] = BS[(size_t)c0i * 64 + lane];
            bms1[n2] = BS[(size_t)(c0i + 16) * 64 + lane];
        }
        // A-prefetch for step os+1 — stays in flight across barrier + all MFMAs
        if (os < 7) {
            int cb = ((os + 1) << 5) + co;
            pea = *(const uint4*)(ea + cb);
            peb = *(const uint4*)(eb + cb);
            pra = *(const uint4*)(ra + cb);
            prb = *(const uint4*)(rb + cb);
            pg  = *(const uint4*)(rg + cb);
        }
        asm volatile("s_waitcnt lgkmcnt(0)" ::: "memory");
        __builtin_amdgcn_s_barrier();
        __builtin_amdgcn_sched_barrier(0);
        int s = lane >> 4, r16 = lane & 15;
        bf16x8 a[4];
        // ml mean x B-half0
        #pragma unroll
        for (int m2 = 0; m2 < 4; ++m2) a[m2] = *(const bf16x8*)(lds + lds_off(m2 * 16 + r16, s));
        __builtin_amdgcn_s_setprio(1);
        #pragma unroll
        for (int m2 = 0; m2 < 4; ++m2)
            #pragma unroll
            for (int n2 = 0; n2 < 4; ++n2)
                accml[m2][n2] = __builtin_amdgcn_mfma_f32_16x16x32_bf16(a[m2], bml0[n2], accml[m2][n2], 0, 0, 0);
        __builtin_amdgcn_s_setprio(0);
        // ml max x B-half1
        #pragma unroll
        for (int m2 = 0; m2 < 4; ++m2) a[m2] = *(const bf16x8*)(lds + 4096 + lds_off(m2 * 16 + r16, s));
        __builtin_amdgcn_s_setprio(1);
        #pragma unroll
        for (int m2 = 0; m2 < 4; ++m2)
            #pragma unroll
            for (int n2 = 0; n2 < 4; ++n2)
                accml[m2][n2] = __builtin_amdgcn_mfma_f32_16x16x32_bf16(a[m2], bml1[n2], accml[m2][n2], 0, 0, 0);
        __builtin_amdgcn_s_setprio(0);
        // ms mean x B-half0
        #pragma unroll
        for (int m2 = 0; m2 < 4; ++m2) a[m2] = *(const bf16x8*)(lds + 8192 + lds_off(m2 * 16 + r16, s));
        __builtin_amdgcn_s_setprio(1);
        #pragma unroll
        for (int m2 = 0; m2 < 4; ++m2)
            #pragma unroll
            for (int n2 = 0; n2 < 4; ++n2)
                accms[m2][n2] = __builtin_amdgcn_mfma_f32_16x16x32_bf16(a[m2], bms0[n2], accms[m2][n2], 0, 0, 0);
        __builtin_amdgcn_s_setprio(0);
        // ms max x B-half1
        #pragma unroll
        for (int m2 = 0; m2 < 4; ++m2) a[m2] = *(const bf16x8*)(lds + 12288 + lds_off(m2 * 16 + r16, s));
        __builtin_amdgcn_s_setprio(1);
        #pragma unroll
        for (int m2 = 0; m2 < 4; ++m2)
            #pragma unroll
            for (int n2 = 0; n2 < 4; ++n2)
                accms[m2][n2] = __builtin_amdgcn_mfma_f32_16x16x32_bf16(a[m2], bms1[n2], accms[m2][n2], 0, 0, 0);
        __builtin_amdgcn_s_setprio(0);
        __builtin_amdgcn_s_barrier();
        __builtin_amdgcn_sched_barrier(0);
    }
    // epilogue: two layer-2 dots, per-edge reductions
    int q = lane >> 4, r16 = lane & 15;
    {
        float b1c[4], w2c[4];
        #pragma unroll
        for (int n2 = 0; n2 < 4; ++n2) {
            int c = (w << 6) + n2 * 16 + r16;
            b1c[n2] = b1ml[c]; w2c[n2] = w2ml[c];
        }
        #pragma unroll
        for (int m2 = 0; m2 < 4; ++m2) {
            #pragma unroll
            for (int i = 0; i < 4; ++i) {
                int row = m2 * 16 + q * 4 + i;
                float ps = 0.f;
                #pragma unroll
                for (int n2 = 0; n2 < 4; ++n2) ps += tanh_fast(accml[m2][n2][i] + b1c[n2]) * w2c[n2];
                ps += __shfl_xor(ps, 1);
                ps += __shfl_xor(ps, 2);
                ps += __shfl_xor(ps, 4);
                ps += __shfl_xor(ps, 8);
                if (r16 == 0) atomicAdd(&redml[row], ps);
            }
        }
    }
    {
        float b1c[4], w2c[4];
        #pragma unroll
        for (int n2 = 0; n2 < 4; ++n2) {
            int c = (w << 6) + n2 * 16 + r16;
            b1c[n2] = b1ms[c]; w2c[n2] = w2ms[c];
        }
        #pragma unroll
        for (int m2 = 0; m2 < 4; ++m2) {
            #pragma unroll
            for (int i = 0; i < 4; ++i) {
                int row = m2 * 16 + q * 4 + i;
                float ps = 0.f;
                #pragma unroll
                for (int n2 = 0; n2 < 4; ++n2) ps += tanh_fast(accms[m2][n2][i] + b1c[n2]) * w2c[n2];
                ps += __shfl_xor(ps, 1);
                ps += __shfl_xor(ps, 2);
                ps += __shfl_xor(ps, 4);
                ps += __shfl_xor(ps, 8);
                if (r16 == 0) atomicAdd(&redms[row], ps);
            }
        }
    }
    simacc += __shfl_xor(simacc, 1);
    simacc += __shfl_xor(simacc, 2);
    if (p == 0) mlsc[e0 + arow] = sigmoid_fast(simacc + sumb[0]);
    __syncthreads();
    if (tid < 64) {
        apml[e0 + tid] = redml[tid];
        apms[e0 + tid] = redms[tid];
    }
}

// ---------------- final ensemble ----------------
__global__ void k_final(const float* __restrict__ apml, const float* __restrict__ apms,
                        const float* __restrict__ mlsc, const float* __restrict__ mstr,
                        const float* __restrict__ pxtr, const int* __restrict__ index,
                        const float* __restrict__ mlb2, const float* __restrict__ msb2,
                        float* __restrict__ out) {
    int e = blockIdx.x * 256 + threadIdx.x;
    if (e >= E_) return;
    float aml = tanh_fast(apml[e] + mlb2[0]);
    float ams = tanh_fast(apms[e] + msb2[0]);
    float apx = PROXW;
    float m = fmaxf(aml, fmaxf(ams, apx));
    float wml = __expf(aml - m), wms = __expf(ams - m), wpx = __expf(apx - m);
    float inv = __builtin_amdgcn_rcpf(wml + wms + wpx);
    int idx = index[e];
    float v = (mlsc[e] * wml + mstr[idx] * wms + pxtr[idx] * wpx) * inv;
    out[e] = fminf(fmaxf(v, 0.f), 1.f);
}

__global__ void k_sentinel(float* out, int n) {
    int i = blockIdx.x * 256 + threadIdx.x;
    if (i < n) out[i] = -12345.0f;
}

// ---------------- launch ----------------
extern "C" void kernel_launch(void* const* d_in, const int* in_sizes, int n_in,
                              void* d_out, int out_size, void* d_ws, size_t ws_size,
                              hipStream_t stream) {
    const float* x     = (const float*)d_in[0];
    const int*   mp    = (const int*)d_in[1];
    const int*   edges = (const int*)d_in[2];
    const int*   index = (const int*)d_in[3];
    const float* p0    = (const float*)d_in[4];
    const float* p1    = (const float*)d_in[5];
    const float* p2    = (const float*)d_in[6];
    const float* gc1W  = (const float*)d_in[7];
    const float* gc1b  = (const float*)d_in[8];
    const float* gc2W  = (const float*)d_in[9];
    const float* gc2b  = (const float*)d_in[10];
    const float* linW  = (const float*)d_in[11];
    const float* linb  = (const float*)d_in[12];
    const float* wlin  = (const float*)d_in[13];
    const float* blin  = (const float*)d_in[14];
    const float* wq    = (const float*)d_in[15];
    const float* wk    = (const float*)d_in[16];
    const float* wv    = (const float*)d_in[17];
    const float* mlw1  = (const float*)d_in[18];
    const float* mlb1  = (const float*)d_in[19];
    const float* mlw2  = (const float*)d_in[20];
    const float* mlb2  = (const float*)d_in[21];
    const float* msw1  = (const float*)d_in[22];
    const float* msb1  = (const float*)d_in[23];
    const float* msw2  = (const float*)d_in[24];
    const float* msb2  = (const float*)d_in[25];
    const float* msdrW = (const float*)d_in[26];
    const float* msdrb = (const float*)d_in[27];
    const float* logits = (const float*)d_in[28];
    const float* mstr  = (const float*)d_in[29];
    const float* pxtr  = (const float*)d_in[30];
    float* out = (float*)d_out;

    const int* src_mp = mp;
    const int* dst_mp = mp + EMP_;
    const int* es = edges;
    const int* ed = edges + E_;

    char* ws = (char*)d_ws;
    size_t off = 0;
    auto alloc = [&](size_t bytes) -> char* {
        off = (off + 255) & ~(size_t)255;
        char* r = ws + off;
        off += bytes;
        return r;
    };
    const size_t NODE_BF = (size_t)Nn_ * 256 * 2;
    unsigned short* W0 = (unsigned short*)alloc(NODE_BF);  // xb -> gb
    unsigned short* W1 = (unsigned short*)alloc(NODE_BF);  // xw1/xw2 -> logitsb
    unsigned short* W2 = (unsigned short*)alloc(NODE_BF);  // hb -> rb
    unsigned short* W3 = (unsigned short*)alloc(NODE_BF);  // embb
    unsigned short* W4 = (unsigned short*)alloc(NODE_BF);  // tb/ub
    unsigned short* W5 = (unsigned short*)alloc(NODE_BF);  // emb2b
    int*   cnt  = (int*)alloc((size_t)Nn_ * 4);
    int*   rowp = (int*)alloc((size_t)(Nn_ + 1) * 4);
    int*   fill = (int*)alloc((size_t)Nn_ * 4);
    int*   csr  = (int*)alloc((size_t)EMP_ * 4);
    float* dinv = (float*)alloc((size_t)Nn_ * 4);
    int*   bsum = (int*)alloc(512 * 4);
    float* Mqk  = (float*)alloc(65536 * 4);
    float* W2wf = (float*)alloc(65536 * 4);
    unsigned short* gc1Wt = (unsigned short*)alloc(65536 * 2);
    unsigned short* gc2Wt = (unsigned short*)alloc(65536 * 2);
    unsigned short* MqkT  = (unsigned short*)alloc(65536 * 2);
    unsigned short* Bt512 = (unsigned short*)alloc(131072 * 2);
    unsigned short* symb  = (unsigned short*)alloc(65536 * 2);
    unsigned short* msdrWt = (unsigned short*)alloc(16384 * 2);
    unsigned short* mlPk  = (unsigned short*)alloc(131072 * 2);
    unsigned short* msPk  = (unsigned short*)alloc(131072 * 2);
    float* apml = (float*)alloc((size_t)E_ * 4);
    float* apms = (float*)alloc((size_t)E_ * 4);
    float* mlsc = (float*)alloc((size_t)E_ * 4);
    float* sumb = (float*)alloc(256);

    if (off > ws_size) {
        k_sentinel<<<(E_ + 255) / 256, 256, 0, stream>>>(out, E_);
        return;
    }

    hipMemsetAsync(cnt, 0, (size_t)Nn_ * 4, stream);
    hipMemsetAsync(fill, 0, (size_t)Nn_ * 4, stream);

    const int NB = (Nn_ + 255) / 256;
    const int EB = (EMP_ + 255) / 256;

    // input conversions + consolidated weight prep
    k_cvt<<<30000, 256, 0, stream>>>(x, W0, Nn_ * 256 / 4);
    k_prep1<<<1153, 256, 0, stream>>>(gc1W, gc2W, msdrW, wlin, blin, mlw1, msw1,
                                      gc1Wt, gc2Wt, msdrWt, symb, sumb, mlPk, msPk);
    dim3 gSmall(4, 4);
    gemm_tiled<true><<<gSmall, 256, 0, stream>>>(wq, wk, Mqk, 256, 256, 256);
    gemm_tiled<false><<<gSmall, 256, 0, stream>>>(wv, linW + 256 * 256, W2wf, 256, 256, 256);
    k_prep2<<<768, 256, 0, stream>>>(Mqk, linW, W2wf, MqkT, Bt512);

    // CSR
    k_count<<<EB, 256, 0, stream>>>(dst_mp, cnt, EMP_);
    k_block_reduce<<<NB, 256, 0, stream>>>(cnt, bsum, Nn_);
    k_scan_bsum<<<1, 64, 0, stream>>>(bsum, NB);
    k_scan_final<<<NB, 256, 0, stream>>>(cnt, bsum, rowp, Nn_, EMP_);
    k_fill<<<EB, 256, 0, stream>>>(src_mp, dst_mp, rowp, fill, csr, EMP_);
    k_dinv<<<NB, 256, 0, stream>>>(cnt, dinv, Nn_);

    dim3 gFull(2, (Nn_ + 127) / 128);
    dim3 gT(2, (P2_ + 127) / 128);
    const int AGG_B = (Nn_ + 3) / 4;

    // GCN layer 1
    mfma_gemm<false, false><<<gFull, 256, 0, stream>>>(W0, W0, 256, 256, gc1Wt, nullptr, W1, Nn_);
    k_agg_bf<<<AGG_B, 256, 0, stream>>>(W1, rowp, csr, dinv, gc1b, W2);
    // GCN layer 2
    mfma_gemm<false, false><<<gFull, 256, 0, stream>>>(W2, W2, 256, 256, gc2Wt, nullptr, W1, Nn_);
    k_agg_bf<<<AGG_B, 256, 0, stream>>>(W1, rowp, csr, dinv, gc2b, W3);

    // attention: t = emb @ Mqk (rows < P2), then u (16 nodes/block)
    mfma_gemm<false, false><<<gT, 256, 0, stream>>>(W3, W3, 256, 256, MqkT, nullptr, W4, P2_);
    k_attn_u2<<<Nn_ / 16, 256, 0, stream>>>(W3, W4, p0, p1, p2, W4);

    // emb2 = tanh([emb|u] @ Bt512^T + linb)
    mfma_gemm<true, true><<<gFull, 256, 0, stream>>>(W3, W4, 256, 512, Bt512, linb, W5, Nn_);

    // g = emb2 @ sym
    mfma_gemm<false, false><<<gFull, 256, 0, stream>>>(W5, W5, 256, 256, symb, nullptr, W0, Nn_);

    // r = tanh(logits @ msdrW + msdrb)
    k_cvt<<<7500, 256, 0, stream>>>(logits, W1, Nn_ * 64 / 4);
    mfma_gemm<true, true><<<gFull, 256, 0, stream>>>(W1, W1, 64, 64, msdrWt, msdrb, W2, Nn_);

    // merged edge MLPs (+fused bilinear sim)
    mfma_edge6<<<E_ / 64, 256, 0, stream>>>(W5, W2, W0, es, ed, mlPk, msPk,
                                            mlb1, mlw2, msb1, msw2, sumb, apml, apms, mlsc);

    // final ensemble
    k_final<<<(E_ + 255) / 256, 256, 0, stream>>>(apml, apms, mlsc, mstr, pxtr, index, mlb2, msb2, out);
}

// Round 10
// 967.490 us; speedup vs baseline: 1.1467x; 1.1467x over previous
//
#include <hip/hip_runtime.h>
#include <hip/hip_bf16.h>

// ---------------- constants ----------------
#define Nn_   120000
#define F_    256
#define H_    256
#define L_    64
#define EMP_  1000000
#define E_    200000
#define P0_   60000
#define P1_   80000
#define P2_   100000
#define PROXW 0.3f

typedef __attribute__((ext_vector_type(8))) short bf16x8;
typedef __attribute__((ext_vector_type(4))) float f32x4;

__device__ inline float bf2f(unsigned short u) {
    union { unsigned int i; float f; } x; x.i = ((unsigned int)u) << 16; return x.f;
}
__device__ inline unsigned short f2bf(float f) {
    union { float f; unsigned int i; } x; x.f = f;
    unsigned int r = x.i + 0x7fffu + ((x.i >> 16) & 1u);
    return (unsigned short)(r >> 16);
}
__device__ inline float tanh_fast(float x) {
    float e = __expf(2.0f * x);
    return 1.0f - 2.0f * __builtin_amdgcn_rcpf(e + 1.0f);
}
__device__ inline float sigmoid_fast(float z) {
    return __builtin_amdgcn_rcpf(1.0f + __expf(-z));
}
__device__ inline int lds_off(int row, int s) {
    return row * 64 + ((s ^ ((row >> 1) & 3)) << 4);
}
__device__ inline void gload_lds16(const void* g, void* l) {
    __builtin_amdgcn_global_load_lds((const __attribute__((address_space(1))) void*)g,
                                     (__attribute__((address_space(3))) void*)l, 16, 0, 0);
}
__device__ inline void unpk8(uint4 u, float* o) {
    o[0] = bf2f(u.x & 0xffff); o[1] = bf2f(u.x >> 16);
    o[2] = bf2f(u.y & 0xffff); o[3] = bf2f(u.y >> 16);
    o[4] = bf2f(u.z & 0xffff); o[5] = bf2f(u.z >> 16);
    o[6] = bf2f(u.w & 0xffff); o[7] = bf2f(u.w >> 16);
}
// mean & max of two packed bf16 pairs; max needs no re-rounding
__device__ inline void meanmax_u(unsigned int ua, unsigned int ub,
                                 unsigned int& um, unsigned int& ux) {
    float alo = __uint_as_float(ua << 16);
    float ahi = __uint_as_float(ua & 0xffff0000u);
    float blo = __uint_as_float(ub << 16);
    float bhi = __uint_as_float(ub & 0xffff0000u);
    um = (unsigned int)f2bf((alo + blo) * 0.5f) |
         ((unsigned int)f2bf((ahi + bhi) * 0.5f) << 16);
    ux = (__float_as_uint(fmaxf(alo, blo)) >> 16) |
         (__float_as_uint(fmaxf(ahi, bhi)) & 0xffff0000u);
}
__device__ inline float dot2_u(unsigned int ug, unsigned int ub) {
    float gl = __uint_as_float(ug << 16);
    float gh = __uint_as_float(ug & 0xffff0000u);
    float bl = __uint_as_float(ub << 16);
    float bh = __uint_as_float(ub & 0xffff0000u);
    return fmaf(gl, bl, gh * bh);
}

// ---------------- CSR build ----------------
__global__ void k_count(const int* __restrict__ dst, int* __restrict__ cnt, int n) {
    int e = blockIdx.x * 256 + threadIdx.x;
    if (e < n) atomicAdd(&cnt[dst[e]], 1);
}
__global__ void k_block_reduce(const int* __restrict__ cnt, int* __restrict__ bsum, int n) {
    __shared__ int s[256];
    int i = blockIdx.x * 256 + threadIdx.x;
    s[threadIdx.x] = (i < n) ? cnt[i] : 0;
    __syncthreads();
    for (int o = 128; o > 0; o >>= 1) {
        if (threadIdx.x < o) s[threadIdx.x] += s[threadIdx.x + o];
        __syncthreads();
    }
    if (threadIdx.x == 0) bsum[blockIdx.x] = s[0];
}
__global__ void k_scan_bsum(int* bsum, int nb) {
    if (threadIdx.x == 0 && blockIdx.x == 0) {
        int acc = 0;
        for (int i = 0; i < nb; i++) { int v = bsum[i]; bsum[i] = acc; acc += v; }
    }
}
__global__ void k_scan_final(const int* __restrict__ cnt, const int* __restrict__ bsum,
                             int* __restrict__ rowp, int n, int etot) {
    __shared__ int s[256];
    int tid = threadIdx.x;
    int i = blockIdx.x * 256 + tid;
    int v = (i < n) ? cnt[i] : 0;
    s[tid] = v;
    __syncthreads();
    for (int o = 1; o < 256; o <<= 1) {
        int t = 0;
        if (tid >= o) t = s[tid - o];
        __syncthreads();
        s[tid] += t;
        __syncthreads();
    }
    if (i < n) rowp[i] = bsum[blockIdx.x] + s[tid] - v;
    if (i == 0 && blockIdx.x == 0) rowp[n] = etot;
}
__global__ void k_fill(const int* __restrict__ src, const int* __restrict__ dst,
                       const int* __restrict__ rowp, int* __restrict__ fill,
                       int* __restrict__ csr, int n) {
    int e = blockIdx.x * 256 + threadIdx.x;
    if (e < n) {
        int d = dst[e];
        int p = atomicAdd(&fill[d], 1);
        csr[rowp[d] + p] = src[e];
    }
}
__global__ void k_dinv(const int* __restrict__ cnt, float* __restrict__ dinv, int n) {
    int i = blockIdx.x * 256 + threadIdx.x;
    if (i < n) dinv[i] = rsqrtf((float)cnt[i] + 1.0f);
}

// ---------------- small f32 tiled GEMM (256^3 precomputes only) ----------------
#define TM 64
#define TN 64
#define TK 16
template <bool TRANSB>
__global__ void gemm_tiled(const float* __restrict__ A, const float* __restrict__ B,
                           float* __restrict__ C, int M, int K, int N) {
    __shared__ float As[TK][TM + 4];
    __shared__ float Bs[TK][TN + 4];
    int tid = threadIdx.x;
    int tx = tid & 15, ty = tid >> 4;
    int row0 = blockIdx.y * TM, col0 = blockIdx.x * TN;
    int lr = tid >> 2, lc4 = (tid & 3) * 4;
    float acc[4][4] = {};
    for (int k0 = 0; k0 < K; k0 += TK) {
        {
            int gr = row0 + lr;
            float4 v = make_float4(0.f, 0.f, 0.f, 0.f);
            if (gr < M) v = *(const float4*)(A + (size_t)gr * K + k0 + lc4);
            As[lc4 + 0][lr] = v.x; As[lc4 + 1][lr] = v.y;
            As[lc4 + 2][lr] = v.z; As[lc4 + 3][lr] = v.w;
        }
        {
            int n = tid & 63, kk0 = tid >> 6;
#pragma unroll
            for (int p = 0; p < 4; p++) {
                int kk = kk0 + p * 4;
                if (TRANSB) Bs[kk][n] = B[(size_t)(col0 + n) * K + k0 + kk];
                else        Bs[kk][n] = B[(size_t)(k0 + kk) * N + col0 + n];
            }
        }
        __syncthreads();
#pragma unroll
        for (int kk = 0; kk < TK; kk++) {
            float4 a = *(const float4*)&As[kk][ty * 4];
            float4 b = *(const float4*)&Bs[kk][tx * 4];
            float av[4] = {a.x, a.y, a.z, a.w};
            float bv[4] = {b.x, b.y, b.z, b.w};
#pragma unroll
            for (int i = 0; i < 4; i++)
#pragma unroll
                for (int j = 0; j < 4; j++) acc[i][j] += av[i] * bv[j];
        }
        __syncthreads();
    }
#pragma unroll
    for (int i = 0; i < 4; i++) {
        int r = row0 + ty * 4 + i;
        if (r >= M) continue;
#pragma unroll
        for (int j = 0; j < 4; j++) C[(size_t)r * N + col0 + tx * 4 + j] = acc[i][j];
    }
}

// ---------------- conversions ----------------
__global__ void k_cvt(const float* __restrict__ in, unsigned short* __restrict__ out, int n4) {
    int i = blockIdx.x * 256 + threadIdx.x;
    if (i >= n4) return;
    float4 v = ((const float4*)in)[i];
    ushort4 o;
    o.x = f2bf(v.x); o.y = f2bf(v.y); o.z = f2bf(v.z); o.w = f2bf(v.w);
    ((ushort4*)out)[i] = o;
}

// Pack Wsrc[512][256] f32 -> fragment layout chunks (see mfma_edge B-read mapping)
__device__ inline void packBF_task(const float* __restrict__ Wsrc,
                                   unsigned short* __restrict__ P, int blk) {
    int t = blk * 256 + threadIdx.x;
    int c = t >> 6, l = t & 63;
    int os = c >> 5, half = (c >> 4) & 1, colb = c & 15;
    int col = (colb << 4) + (l & 15);
    int k = (half << 8) + (os << 5) + ((l >> 4) << 3);
    bf16x8 v;
#pragma unroll
    for (int j = 0; j < 8; ++j) v[j] = (short)f2bf(Wsrc[(size_t)(k + j) * 256 + col]);
    *(bf16x8*)(P + (size_t)t * 8) = v;
}

// consolidated weight prep #1 (input-only deps): 1153 blocks
__global__ void k_prep1(const float* __restrict__ gc1W, const float* __restrict__ gc2W,
                        const float* __restrict__ msdrW, const float* __restrict__ wlin,
                        const float* __restrict__ blin, const float* __restrict__ mlw1,
                        const float* __restrict__ msw1,
                        unsigned short* __restrict__ gc1Wt, unsigned short* __restrict__ gc2Wt,
                        unsigned short* __restrict__ msdrWt, unsigned short* __restrict__ symb,
                        float* __restrict__ sumb, unsigned short* __restrict__ mlPk,
                        unsigned short* __restrict__ msPk) {
    __shared__ float s[256];
    int b = blockIdx.x, tid = threadIdx.x;
    if (b < 256) {
        int c = b;
        for (int r = tid; r < 256; r += 256) gc1Wt[c * 256 + r] = f2bf(gc1W[(size_t)r * 256 + c]);
    } else if (b < 512) {
        int c = b - 256;
        for (int r = tid; r < 256; r += 256) gc2Wt[c * 256 + r] = f2bf(gc2W[(size_t)r * 256 + c]);
    } else if (b < 768) {
        int c = b - 512;
        if (tid < 64) msdrWt[c * 64 + tid] = f2bf(msdrW[(size_t)tid * 256 + c]);
    } else if (b < 1024) {
        int r = b - 768, c = tid;
        symb[r * 256 + c] = f2bf(0.5f * (wlin[r * 256 + c] + wlin[c * 256 + r]));
    } else if (b == 1024) {
        s[tid] = blin[tid];
        __syncthreads();
        for (int o = 128; o > 0; o >>= 1) {
            if (tid < o) s[tid] += s[tid + o];
            __syncthreads();
        }
        if (tid == 0) sumb[0] = s[0];
    } else if (b < 1089) {
        packBF_task(mlw1, mlPk, b - 1025);
    } else {
        packBF_task(msw1, msPk, b - 1089);
    }
}
// consolidated weight prep #2 (after gemm_tiled): 768 blocks
__global__ void k_prep2(const float* __restrict__ Mqk, const float* __restrict__ linW,
                        const float* __restrict__ W2w, unsigned short* __restrict__ MqkT,
                        unsigned short* __restrict__ Bt) {
    int b = blockIdx.x, tid = threadIdx.x;
    if (b < 256) {
        int c = b;
        for (int r = tid; r < 256; r += 256) MqkT[c * 256 + r] = f2bf(Mqk[(size_t)r * 256 + c]);
    } else {
        int idx = (b - 256) * 256 + tid;
        int n = idx >> 9, k = idx & 511;
        float v = (k < 256) ? linW[(size_t)k * 256 + n] : W2w[(size_t)(k - 256) * 256 + n];
        Bt[idx] = f2bf(v);
    }
}

// ---------------- GCN aggregation: one wave per node, 2-deep neighbor prefetch ----------------
__global__ __launch_bounds__(256)
void k_agg_bf(const unsigned short* __restrict__ xw, const int* __restrict__ rowp,
              const int* __restrict__ csr, const float* __restrict__ dinv,
              const float* __restrict__ bias, unsigned short* __restrict__ out) {
    int w = threadIdx.x >> 6, lane = threadIdx.x & 63;
    int v = blockIdx.x * 4 + w;
    if (v >= Nn_) return;
    const uint2* x64 = (const uint2*)xw;
    float a0 = 0.f, a1 = 0.f, a2 = 0.f, a3 = 0.f;
    int beg = rowp[v], end = rowp[v + 1];
    uint2 u0 = make_uint2(0, 0), u1 = make_uint2(0, 0);
    float d0 = 0.f, d1 = 0.f;
    if (beg < end) {
        int s = csr[beg];
        d0 = dinv[s];
        u0 = x64[(size_t)s * 64 + lane];
    }
    if (beg + 1 < end) {
        int s = csr[beg + 1];
        d1 = dinv[s];
        u1 = x64[(size_t)s * 64 + lane];
    }
    for (int p = beg; p < end; ++p) {
        uint2 uc = u0; float dc = d0;
        u0 = u1; d0 = d1;
        if (p + 2 < end) {
            int s = csr[p + 2];
            d1 = dinv[s];
            u1 = x64[(size_t)s * 64 + lane];
        }
        a0 += bf2f(uc.x & 0xffff) * dc;
        a1 += bf2f(uc.x >> 16) * dc;
        a2 += bf2f(uc.y & 0xffff) * dc;
        a3 += bf2f(uc.y >> 16) * dc;
    }
    float dv = dinv[v];
    uint2 us = x64[(size_t)v * 64 + lane];
    a0 = a0 * dv + bf2f(us.x & 0xffff) * dv * dv;
    a1 = a1 * dv + bf2f(us.x >> 16) * dv * dv;
    a2 = a2 * dv + bf2f(us.y & 0xffff) * dv * dv;
    a3 = a3 * dv + bf2f(us.y >> 16) * dv * dv;
    int c0 = lane * 4;
    float4 bv = *(const float4*)(bias + c0);
    uint2 ov;
    ov.x = (unsigned int)f2bf(tanh_fast(a0 + bv.x)) |
           ((unsigned int)f2bf(tanh_fast(a1 + bv.y)) << 16);
    ov.y = (unsigned int)f2bf(tanh_fast(a2 + bv.z)) |
           ((unsigned int)f2bf(tanh_fast(a3 + bv.w)) << 16);
    ((uint2*)out)[(size_t)v * 64 + lane] = ov;
}

// ---------------- MFMA GEMM, dbuf LDS + raw barriers + counted vmcnt ----------------
template <bool BIAS, bool TANH>
__global__ __launch_bounds__(256)
void mfma_gemm(const unsigned short* __restrict__ A0, const unsigned short* __restrict__ A1,
               int Ksplit, int K, const unsigned short* __restrict__ Bt,
               const float* __restrict__ bias, unsigned short* __restrict__ Cb, int M) {
    __shared__ char lds[2][16384];
    int tid = threadIdx.x, lane = tid & 63, w = tid >> 6;
    int row0 = blockIdx.y * 128, col0 = blockIdx.x * 128;
    int wr = w >> 1, wc = w & 1;
    f32x4 acc[4][4] = {};
    int nk = K >> 5;

    auto stage = [&](int ks, int buf) {
        int k0 = ks << 5;
        #pragma unroll
        for (int j = 0; j < 4; ++j) {
            int ins = w + (j << 2);
            int lrow = ((ins & 7) << 4) + (lane >> 2);
            int p = lane & 3;
            int slog = p ^ ((lrow >> 1) & 3);
            char* ldst = lds[buf] + ((ins & 7) << 10) + ((ins >= 8) ? 8192 : 0);
            const unsigned short* src;
            if (ins < 8) {
                int grow = row0 + lrow;
                if (grow >= M) grow = M - 1;
                const unsigned short* Asrc; int kk, pitch;
                if (k0 < Ksplit) { Asrc = A0; kk = k0; pitch = Ksplit; }
                else             { Asrc = A1; kk = k0 - Ksplit; pitch = K - Ksplit; }
                src = Asrc + (size_t)grow * pitch + kk + (slog << 3);
            } else {
                int grow = col0 + lrow;
                src = Bt + (size_t)grow * K + k0 + (slog << 3);
            }
            gload_lds16(src, ldst);
        }
    };

    stage(0, 0);
    for (int ks = 0; ks < nk; ++ks) {
        int cur = ks & 1;
        if (ks + 1 < nk) {
            stage(ks + 1, cur ^ 1);
            asm volatile("s_waitcnt vmcnt(4)" ::: "memory");
        } else {
            asm volatile("s_waitcnt vmcnt(0)" ::: "memory");
        }
        __builtin_amdgcn_s_barrier();
        __builtin_amdgcn_sched_barrier(0);
        int s = lane >> 4, r16 = lane & 15;
        bf16x8 a[4], b[4];
        #pragma unroll
        for (int m = 0; m < 4; ++m) a[m] = *(const bf16x8*)(lds[cur] + lds_off(wr * 64 + m * 16 + r16, s));
        #pragma unroll
        for (int n = 0; n < 4; ++n) b[n] = *(const bf16x8*)(lds[cur] + 8192 + lds_off(wc * 64 + n * 16 + r16, s));
        __builtin_amdgcn_s_setprio(1);
        #pragma unroll
        for (int m = 0; m < 4; ++m)
            #pragma unroll
            for (int n = 0; n < 4; ++n)
                acc[m][n] = __builtin_amdgcn_mfma_f32_16x16x32_bf16(a[m], b[n], acc[m][n], 0, 0, 0);
        __builtin_amdgcn_s_setprio(0);
        __builtin_amdgcn_s_barrier();
        __builtin_amdgcn_sched_barrier(0);
    }
    int q = lane >> 4, r16 = lane & 15;
    float bv[4];
    #pragma unroll
    for (int n = 0; n < 4; ++n) bv[n] = BIAS ? bias[col0 + wc * 64 + n * 16 + r16] : 0.f;
    #pragma unroll
    for (int m = 0; m < 4; ++m) {
        #pragma unroll
        for (int i = 0; i < 4; ++i) {
            int row = row0 + wr * 64 + m * 16 + q * 4 + i;
            if (row >= M) continue;
            #pragma unroll
            for (int n = 0; n < 4; ++n) {
                int col = col0 + wc * 64 + n * 16 + r16;
                float v = acc[m][n][i];
                if (BIAS) v += bv[n];
                if (TANH) v = tanh_fast(v);
                Cb[(size_t)row * 256 + col] = f2bf(v);
            }
        }
    }
}

// ---------------- attention u: 16 lanes/node, online softmax ----------------
__global__ __launch_bounds__(256)
void k_attn_u2(const unsigned short* __restrict__ emb, const unsigned short* __restrict__ t,
               const float* __restrict__ p0, const float* __restrict__ p1,
               const float* __restrict__ p2, unsigned short* __restrict__ u) {
    int tid = threadIdx.x;
    int g = tid >> 4, l = tid & 15;
    int n = blockIdx.x * 16 + g;
    size_t eoff = (size_t)n * 256 + l * 16;
    const uint4* e16 = (const uint4*)(emb + eoff);
    uint4* u16 = (uint4*)(u + eoff);
    uint4 eb0 = e16[0], eb1 = e16[1];
    if (n >= P2_) { u16[0] = eb0; u16[1] = eb1; return; }
    float tv[16], ev[16];
    {
        const uint4* t16 = (const uint4*)(t + eoff);
        unpk8(t16[0], tv); unpk8(t16[1], tv + 8);
        unpk8(eb0, ev); unpk8(eb1, ev + 8);
    }
    float m = -3.0e38f, den = 0.f, o[16];
    #pragma unroll
    for (int i = 0; i < 16; i++) o[i] = 0.f;
    auto accum = [&](const float* sv) {
        float dt = 0.f;
        #pragma unroll
        for (int i = 0; i < 16; i++) dt += tv[i] * sv[i];
        dt += __shfl_xor(dt, 1);
        dt += __shfl_xor(dt, 2);
        dt += __shfl_xor(dt, 4);
        dt += __shfl_xor(dt, 8);
        float lg = dt * 0.0625f;
        float mn = fmaxf(m, lg);
        float s0 = __expf(m - mn), s1 = __expf(lg - mn);
        den = den * s0 + s1;
        #pragma unroll
        for (int i = 0; i < 16; i++) o[i] = o[i] * s0 + s1 * sv[i];
        m = mn;
    };
    auto accum_f32 = [&](const float* base) {
        float sv[16];
        const float4* b4 = (const float4*)(base + eoff);
        #pragma unroll
        for (int i = 0; i < 4; i++) {
            float4 q = b4[i];
            sv[4 * i] = q.x; sv[4 * i + 1] = q.y; sv[4 * i + 2] = q.z; sv[4 * i + 3] = q.w;
        }
        accum(sv);
    };
    if (n < P0_)      { accum_f32(p0); accum_f32(p1); accum_f32(p2); }
    else if (n < P1_) { accum_f32(p1); accum_f32(p2); }
    else              { accum_f32(p2); }
    accum(ev);
    float inv = __builtin_amdgcn_rcpf(den);
    unsigned short h[16];
    #pragma unroll
    for (int i = 0; i < 16; i++) h[i] = f2bf(o[i] * inv);
    uint4 r0, r1;
    r0.x = h[0] | ((unsigned int)h[1] << 16);  r0.y = h[2] | ((unsigned int)h[3] << 16);
    r0.z = h[4] | ((unsigned int)h[5] << 16);  r0.w = h[6] | ((unsigned int)h[7] << 16);
    r1.x = h[8] | ((unsigned int)h[9] << 16);  r1.y = h[10] | ((unsigned int)h[11] << 16);
    r1.z = h[12] | ((unsigned int)h[13] << 16); r1.w = h[14] | ((unsigned int)h[15] << 16);
    u16[0] = r0; u16[1] = r1;
}

// ---------------- fused edge MLP v3': 256 thr, 64 edges, B direct-to-reg, both halves before prefetch ----------------
template <bool SIM>
__global__ __launch_bounds__(256)
void mfma_edge3(const unsigned short* __restrict__ srcemb, const unsigned short* __restrict__ gsrc,
                const int* __restrict__ es, const int* __restrict__ ed,
                const unsigned short* __restrict__ PkF, const float* __restrict__ b1,
                const float* __restrict__ w2, const float* __restrict__ sumb,
                float* __restrict__ a_pre, float* __restrict__ mlsc) {
    __shared__ char lds[8192];    // A: mean 4K | max 4K
    __shared__ float red[64];
    int tid = threadIdx.x, lane = tid & 63, w = tid >> 6;
    int e0 = blockIdx.x * 64;
    int arow = tid >> 2, p = tid & 3;
    int ia = es[e0 + arow], ib = ed[e0 + arow];
    const unsigned short* ra = srcemb + (size_t)ia * 256;
    const unsigned short* rb = srcemb + (size_t)ib * 256;
    const unsigned short* rg = SIM ? (gsrc + (size_t)ia * 256) : nullptr;
    int slog = p ^ ((arow >> 1) & 3);
    int abase = arow * 64 + (p << 4);
    if (tid < 64) red[tid] = 0.f;
    float simacc = 0.f;
    f32x4 acc[4][4] = {};
    // prologue: prefetch step-0 A slices into registers
    uint4 pa = *(const uint4*)(ra + (slog << 3));
    uint4 pb = *(const uint4*)(rb + (slog << 3));
    uint4 pg = make_uint4(0, 0, 0, 0);
    if (SIM) pg = *(const uint4*)(rg + (slog << 3));
    const bf16x8* BF = (const bf16x8*)PkF;   // chunk c: BF[c*64 + lane]
    for (int os = 0; os < 8; ++os) {
        // A convert + swizzled ds_write (compiler waits on pa/pb/pg)
        {
            unsigned int m0, x0, m1, x1, m2, x2, m3, x3;
            meanmax_u(pa.x, pb.x, m0, x0);
            meanmax_u(pa.y, pb.y, m1, x1);
            meanmax_u(pa.z, pb.z, m2, x2);
            meanmax_u(pa.w, pb.w, m3, x3);
            *(uint4*)(lds + abase) = make_uint4(m0, m1, m2, m3);
            *(uint4*)(lds + 4096 + abase) = make_uint4(x0, x1, x2, x3);
            if (SIM)
                simacc += dot2_u(pg.x, pb.x) + dot2_u(pg.y, pb.y) +
                          dot2_u(pg.z, pb.z) + dot2_u(pg.w, pb.w);
        }
        // BOTH B-half fragments loaded BEFORE the A-prefetch (vmcnt is FIFO:
        // loads issued after the prefetch would force it to drain at the MFMA wait)
        bf16x8 b0[4], b1f[4];
        #pragma unroll
        for (int n2 = 0; n2 < 4; ++n2) {
            int c0i = (os << 5) + (w << 2) + n2;
            b0[n2]  = BF[(size_t)c0i * 64 + lane];
            b1f[n2] = BF[(size_t)(c0i + 16) * 64 + lane];
        }
        // A prefetch for step os+1 (newest loads -> stay in flight across whole step)
        if (os < 7) {
            int cb = ((os + 1) << 5) + (slog << 3);
            pa = *(const uint4*)(ra + cb);
            pb = *(const uint4*)(rb + cb);
            if (SIM) pg = *(const uint4*)(rg + cb);
        }
        asm volatile("s_waitcnt lgkmcnt(0)" ::: "memory");   // A ds_writes visible
        __builtin_amdgcn_s_barrier();
        __builtin_amdgcn_sched_barrier(0);
        int s = lane >> 4, r16 = lane & 15;
        {
            bf16x8 a[4];
            #pragma unroll
            for (int m2 = 0; m2 < 4; ++m2)
                a[m2] = *(const bf16x8*)(lds + lds_off(m2 * 16 + r16, s));
            __builtin_amdgcn_s_setprio(1);
            #pragma unroll
            for (int m2 = 0; m2 < 4; ++m2)
                #pragma unroll
                for (int n2 = 0; n2 < 4; ++n2)
                    acc[m2][n2] = __builtin_amdgcn_mfma_f32_16x16x32_bf16(a[m2], b0[n2], acc[m2][n2], 0, 0, 0);
            __builtin_amdgcn_s_setprio(0);
        }
        {
            bf16x8 a[4];
            #pragma unroll
            for (int m2 = 0; m2 < 4; ++m2)
                a[m2] = *(const bf16x8*)(lds + 4096 + lds_off(m2 * 16 + r16, s));
            __builtin_amdgcn_s_setprio(1);
            #pragma unroll
            for (int m2 = 0; m2 < 4; ++m2)
                #pragma unroll
                for (int n2 = 0; n2 < 4; ++n2)
                    acc[m2][n2] = __builtin_amdgcn_mfma_f32_16x16x32_bf16(a[m2], b1f[n2], acc[m2][n2], 0, 0, 0);
            __builtin_amdgcn_s_setprio(0);
        }
        __builtin_amdgcn_s_barrier();
        __builtin_amdgcn_sched_barrier(0);
    }
    // epilogue: layer-2 dot, reduce to per-edge scalar
    int q = lane >> 4, r16 = lane & 15;
    float b1c[4], w2c[4];
    #pragma unroll
    for (int n2 = 0; n2 < 4; ++n2) {
        int c = (w << 6) + n2 * 16 + r16;
        b1c[n2] = b1[c]; w2c[n2] = w2[c];
    }
    #pragma unroll
    for (int m2 = 0; m2 < 4; ++m2) {
        #pragma unroll
        for (int i = 0; i < 4; ++i) {
            int row = m2 * 16 + q * 4 + i;
            float ps = 0.f;
            #pragma unroll
            for (int n2 = 0; n2 < 4; ++n2) ps += tanh_fast(acc[m2][n2][i] + b1c[n2]) * w2c[n2];
            ps += __shfl_xor(ps, 1);
            ps += __shfl_xor(ps, 2);
            ps += __shfl_xor(ps, 4);
            ps += __shfl_xor(ps, 8);
            if (r16 == 0) atomicAdd(&red[row], ps);
        }
    }
    if (SIM) {
        simacc += __shfl_xor(simacc, 1);
        simacc += __shfl_xor(simacc, 2);
        if (p == 0) mlsc[e0 + arow] = sigmoid_fast(simacc + sumb[0]);
    }
    __syncthreads();
    if (tid < 64) a_pre[e0 + tid] = red[tid];
}

// ---------------- final ensemble ----------------
__global__ void k_final(const float* __restrict__ apml, const float* __restrict__ apms,
                        const float* __restrict__ mlsc, const float* __restrict__ mstr,
                        const float* __restrict__ pxtr, const int* __restrict__ index,
                        const float* __restrict__ mlb2, const float* __restrict__ msb2,
                        float* __restrict__ out) {
    int e = blockIdx.x * 256 + threadIdx.x;
    if (e >= E_) return;
    float aml = tanh_fast(apml[e] + mlb2[0]);
    float ams = tanh_fast(apms[e] + msb2[0]);
    float apx = PROXW;
    float m = fmaxf(aml, fmaxf(ams, apx));
    float wml = __expf(aml - m), wms = __expf(ams - m), wpx = __expf(apx - m);
    float inv = __builtin_amdgcn_rcpf(wml + wms + wpx);
    int idx = index[e];
    float v = (mlsc[e] * wml + mstr[idx] * wms + pxtr[idx] * wpx) * inv;
    out[e] = fminf(fmaxf(v, 0.f), 1.f);
}

__global__ void k_sentinel(float* out, int n) {
    int i = blockIdx.x * 256 + threadIdx.x;
    if (i < n) out[i] = -12345.0f;
}

// ---------------- launch ----------------
extern "C" void kernel_launch(void* const* d_in, const int* in_sizes, int n_in,
                              void* d_out, int out_size, void* d_ws, size_t ws_size,
                              hipStream_t stream) {
    const float* x     = (const float*)d_in[0];
    const int*   mp    = (const int*)d_in[1];
    const int*   edges = (const int*)d_in[2];
    const int*   index = (const int*)d_in[3];
    const float* p0    = (const float*)d_in[4];
    const float* p1    = (const float*)d_in[5];
    const float* p2    = (const float*)d_in[6];
    const float* gc1W  = (const float*)d_in[7];
    const float* gc1b  = (const float*)d_in[8];
    const float* gc2W  = (const float*)d_in[9];
    const float* gc2b  = (const float*)d_in[10];
    const float* linW  = (const float*)d_in[11];
    const float* linb  = (const float*)d_in[12];
    const float* wlin  = (const float*)d_in[13];
    const float* blin  = (const float*)d_in[14];
    const float* wq    = (const float*)d_in[15];
    const float* wk    = (const float*)d_in[16];
    const float* wv    = (const float*)d_in[17];
    const float* mlw1  = (const float*)d_in[18];
    const float* mlb1  = (const float*)d_in[19];
    const float* mlw2  = (const float*)d_in[20];
    const float* mlb2  = (const float*)d_in[21];
    const float* msw1  = (const float*)d_in[22];
    const float* msb1  = (const float*)d_in[23];
    const float* msw2  = (const float*)d_in[24];
    const float* msb2  = (const float*)d_in[25];
    const float* msdrW = (const float*)d_in[26];
    const float* msdrb = (const float*)d_in[27];
    const float* logits = (const float*)d_in[28];
    const float* mstr  = (const float*)d_in[29];
    const float* pxtr  = (const float*)d_in[30];
    float* out = (float*)d_out;

    const int* src_mp = mp;
    const int* dst_mp = mp + EMP_;
    const int* es = edges;
    const int* ed = edges + E_;

    char* ws = (char*)d_ws;
    size_t off = 0;
    auto alloc = [&](size_t bytes) -> char* {
        off = (off + 255) & ~(size_t)255;
        char* r = ws + off;
        off += bytes;
        return r;
    };
    const size_t NODE_BF = (size_t)Nn_ * 256 * 2;
    unsigned short* W0 = (unsigned short*)alloc(NODE_BF);  // xb -> gb
    unsigned short* W1 = (unsigned short*)alloc(NODE_BF);  // xw1/xw2 -> logitsb
    unsigned short* W2 = (unsigned short*)alloc(NODE_BF);  // hb -> rb
    unsigned short* W3 = (unsigned short*)alloc(NODE_BF);  // embb
    unsigned short* W4 = (unsigned short*)alloc(NODE_BF);  // tb/ub
    unsigned short* W5 = (unsigned short*)alloc(NODE_BF);  // emb2b
    int*   cnt  = (int*)alloc((size_t)Nn_ * 4);
    int*   rowp = (int*)alloc((size_t)(Nn_ + 1) * 4);
    int*   fill = (int*)alloc((size_t)Nn_ * 4);
    int*   csr  = (int*)alloc((size_t)EMP_ * 4);
    float* dinv = (float*)alloc((size_t)Nn_ * 4);
    int*   bsum = (int*)alloc(512 * 4);
    float* Mqk  = (float*)alloc(65536 * 4);
    float* W2wf = (float*)alloc(65536 * 4);
    unsigned short* gc1Wt = (unsigned short*)alloc(65536 * 2);
    unsigned short* gc2Wt = (unsigned short*)alloc(65536 * 2);
    unsigned short* MqkT  = (unsigned short*)alloc(65536 * 2);
    unsigned short* Bt512 = (unsigned short*)alloc(131072 * 2);
    unsigned short* symb  = (unsigned short*)alloc(65536 * 2);
    unsigned short* msdrWt = (unsigned short*)alloc(16384 * 2);
    unsigned short* mlPk  = (unsigned short*)alloc(131072 * 2);
    unsigned short* msPk  = (unsigned short*)alloc(131072 * 2);
    float* apml = (float*)alloc((size_t)E_ * 4);
    float* apms = (float*)alloc((size_t)E_ * 4);
    float* mlsc = (float*)alloc((size_t)E_ * 4);
    float* sumb = (float*)alloc(256);

    if (off > ws_size) {
        k_sentinel<<<(E_ + 255) / 256, 256, 0, stream>>>(out, E_);
        return;
    }

    hipMemsetAsync(cnt, 0, (size_t)Nn_ * 4, stream);
    hipMemsetAsync(fill, 0, (size_t)Nn_ * 4, stream);

    const int NB = (Nn_ + 255) / 256;
    const int EB = (EMP_ + 255) / 256;

    // input conversions + consolidated weight prep
    k_cvt<<<30000, 256, 0, stream>>>(x, W0, Nn_ * 256 / 4);
    k_prep1<<<1153, 256, 0, stream>>>(gc1W, gc2W, msdrW, wlin, blin, mlw1, msw1,
                                      gc1Wt, gc2Wt, msdrWt, symb, sumb, mlPk, msPk);
    dim3 gSmall(4, 4);
    gemm_tiled<true><<<gSmall, 256, 0, stream>>>(wq, wk, Mqk, 256, 256, 256);
    gemm_tiled<false><<<gSmall, 256, 0, stream>>>(wv, linW + 256 * 256, W2wf, 256, 256, 256);
    k_prep2<<<768, 256, 0, stream>>>(Mqk, linW, W2wf, MqkT, Bt512);

    // CSR
    k_count<<<EB, 256, 0, stream>>>(dst_mp, cnt, EMP_);
    k_block_reduce<<<NB, 256, 0, stream>>>(cnt, bsum, Nn_);
    k_scan_bsum<<<1, 64, 0, stream>>>(bsum, NB);
    k_scan_final<<<NB, 256, 0, stream>>>(cnt, bsum, rowp, Nn_, EMP_);
    k_fill<<<EB, 256, 0, stream>>>(src_mp, dst_mp, rowp, fill, csr, EMP_);
    k_dinv<<<NB, 256, 0, stream>>>(cnt, dinv, Nn_);

    dim3 gFull(2, (Nn_ + 127) / 128);
    dim3 gT(2, (P2_ + 127) / 128);
    const int AGG_B = (Nn_ + 3) / 4;

    // GCN layer 1
    mfma_gemm<false, false><<<gFull, 256, 0, stream>>>(W0, W0, 256, 256, gc1Wt, nullptr, W1, Nn_);
    k_agg_bf<<<AGG_B, 256, 0, stream>>>(W1, rowp, csr, dinv, gc1b, W2);
    // GCN layer 2
    mfma_gemm<false, false><<<gFull, 256, 0, stream>>>(W2, W2, 256, 256, gc2Wt, nullptr, W1, Nn_);
    k_agg_bf<<<AGG_B, 256, 0, stream>>>(W1, rowp, csr, dinv, gc2b, W3);

    // attention: t = emb @ Mqk (rows < P2), then u (16 nodes/block)
    mfma_gemm<false, false><<<gT, 256, 0, stream>>>(W3, W3, 256, 256, MqkT, nullptr, W4, P2_);
    k_attn_u2<<<Nn_ / 16, 256, 0, stream>>>(W3, W4, p0, p1, p2, W4);

    // emb2 = tanh([emb|u] @ Bt512^T + linb)
    mfma_gemm<true, true><<<gFull, 256, 0, stream>>>(W3, W4, 256, 512, Bt512, linb, W5, Nn_);

    // g = emb2 @ sym
    mfma_gemm<false, false><<<gFull, 256, 0, stream>>>(W5, W5, 256, 256, symb, nullptr, W0, Nn_);

    // r = tanh(logits @ msdrW + msdrb)
    k_cvt<<<7500, 256, 0, stream>>>(logits, W1, Nn_ * 64 / 4);
    mfma_gemm<true, true><<<gFull, 256, 0, stream>>>(W1, W1, 64, 64, msdrWt, msdrb, W2, Nn_);

    // edge MLPs (+fused bilinear sim in the ml pass)
    mfma_edge3<true><<<E_ / 64, 256, 0, stream>>>(W5, W0, es, ed, mlPk, mlb1, mlw2, sumb, apml, mlsc);
    mfma_edge3<false><<<E_ / 64, 256, 0, stream>>>(W2, nullptr, es, ed, msPk, msb1, msw2, sumb, apms, nullptr);

    // final ensemble
    k_final<<<(E_ + 255) / 256, 256, 0, stream>>>(apml, apms, mlsc, mstr, pxtr, index, mlb2, msb2, out);
}

// Round 11
// 946.700 us; speedup vs baseline: 1.1719x; 1.0220x over previous
//
#include <hip/hip_runtime.h>
#include <hip/hip_bf16.h>

// ---------------- constants ----------------
#define Nn_   120000
#define F_    256
#define H_    256
#define L_    64
#define EMP_  1000000
#define E_    200000
#define P0_   60000
#define P1_   80000
#define P2_   100000
#define PROXW 0.3f

typedef __attribute__((ext_vector_type(8))) short bf16x8;
typedef __attribute__((ext_vector_type(4))) float f32x4;

__device__ inline float bf2f(unsigned short u) {
    union { unsigned int i; float f; } x; x.i = ((unsigned int)u) << 16; return x.f;
}
__device__ inline unsigned short f2bf(float f) {
    union { float f; unsigned int i; } x; x.f = f;
    unsigned int r = x.i + 0x7fffu + ((x.i >> 16) & 1u);
    return (unsigned short)(r >> 16);
}
__device__ inline float tanh_fast(float x) {
    float e = __expf(2.0f * x);
    return 1.0f - 2.0f * __builtin_amdgcn_rcpf(e + 1.0f);
}
__device__ inline float sigmoid_fast(float z) {
    return __builtin_amdgcn_rcpf(1.0f + __expf(-z));
}
__device__ inline int lds_off(int row, int s) {
    return row * 64 + ((s ^ ((row >> 1) & 3)) << 4);
}
__device__ inline void gload_lds16(const void* g, void* l) {
    __builtin_amdgcn_global_load_lds((const __attribute__((address_space(1))) void*)g,
                                     (__attribute__((address_space(3))) void*)l, 16, 0, 0);
}
__device__ inline void unpk8(uint4 u, float* o) {
    o[0] = bf2f(u.x & 0xffff); o[1] = bf2f(u.x >> 16);
    o[2] = bf2f(u.y & 0xffff); o[3] = bf2f(u.y >> 16);
    o[4] = bf2f(u.z & 0xffff); o[5] = bf2f(u.z >> 16);
    o[6] = bf2f(u.w & 0xffff); o[7] = bf2f(u.w >> 16);
}
// mean & max of two packed bf16 pairs; max needs no re-rounding
__device__ inline void meanmax_u(unsigned int ua, unsigned int ub,
                                 unsigned int& um, unsigned int& ux) {
    float alo = __uint_as_float(ua << 16);
    float ahi = __uint_as_float(ua & 0xffff0000u);
    float blo = __uint_as_float(ub << 16);
    float bhi = __uint_as_float(ub & 0xffff0000u);
    um = (unsigned int)f2bf((alo + blo) * 0.5f) |
         ((unsigned int)f2bf((ahi + bhi) * 0.5f) << 16);
    ux = (__float_as_uint(fmaxf(alo, blo)) >> 16) |
         (__float_as_uint(fmaxf(ahi, bhi)) & 0xffff0000u);
}
__device__ inline float dot2_u(unsigned int ug, unsigned int ub) {
    float gl = __uint_as_float(ug << 16);
    float gh = __uint_as_float(ug & 0xffff0000u);
    float bl = __uint_as_float(ub << 16);
    float bh = __uint_as_float(ub & 0xffff0000u);
    return fmaf(gl, bl, gh * bh);
}

// ---------------- CSR build ----------------
__global__ void k_count(const int* __restrict__ dst, int* __restrict__ cnt, int n) {
    int e = blockIdx.x * 256 + threadIdx.x;
    if (e < n) atomicAdd(&cnt[dst[e]], 1);
}
__global__ void k_block_reduce(const int* __restrict__ cnt, int* __restrict__ bsum, int n) {
    __shared__ int s[256];
    int i = blockIdx.x * 256 + threadIdx.x;
    s[threadIdx.x] = (i < n) ? cnt[i] : 0;
    __syncthreads();
    for (int o = 128; o > 0; o >>= 1) {
        if (threadIdx.x < o) s[threadIdx.x] += s[threadIdx.x + o];
        __syncthreads();
    }
    if (threadIdx.x == 0) bsum[blockIdx.x] = s[0];
}
__global__ void k_scan_bsum(int* bsum, int nb) {
    if (threadIdx.x == 0 && blockIdx.x == 0) {
        int acc = 0;
        for (int i = 0; i < nb; i++) { int v = bsum[i]; bsum[i] = acc; acc += v; }
    }
}
__global__ void k_scan_final(const int* __restrict__ cnt, const int* __restrict__ bsum,
                             int* __restrict__ rowp, int n, int etot) {
    __shared__ int s[256];
    int tid = threadIdx.x;
    int i = blockIdx.x * 256 + tid;
    int v = (i < n) ? cnt[i] : 0;
    s[tid] = v;
    __syncthreads();
    for (int o = 1; o < 256; o <<= 1) {
        int t = 0;
        if (tid >= o) t = s[tid - o];
        __syncthreads();
        s[tid] += t;
        __syncthreads();
    }
    if (i < n) rowp[i] = bsum[blockIdx.x] + s[tid] - v;
    if (i == 0 && blockIdx.x == 0) rowp[n] = etot;
}
__global__ void k_fill(const int* __restrict__ src, const int* __restrict__ dst,
                       const int* __restrict__ rowp, int* __restrict__ fill,
                       int* __restrict__ csr, int n) {
    int e = blockIdx.x * 256 + threadIdx.x;
    if (e < n) {
        int d = dst[e];
        int p = atomicAdd(&fill[d], 1);
        csr[rowp[d] + p] = src[e];
    }
}
__global__ void k_dinv(const int* __restrict__ cnt, float* __restrict__ dinv, int n) {
    int i = blockIdx.x * 256 + threadIdx.x;
    if (i < n) dinv[i] = rsqrtf((float)cnt[i] + 1.0f);
}

// ---------------- small f32 tiled GEMM (256^3 precomputes only) ----------------
#define TM 64
#define TN 64
#define TK 16
template <bool TRANSB>
__global__ void gemm_tiled(const float* __restrict__ A, const float* __restrict__ B,
                           float* __restrict__ C, int M, int K, int N) {
    __shared__ float As[TK][TM + 4];
    __shared__ float Bs[TK][TN + 4];
    int tid = threadIdx.x;
    int tx = tid & 15, ty = tid >> 4;
    int row0 = blockIdx.y * TM, col0 = blockIdx.x * TN;
    int lr = tid >> 2, lc4 = (tid & 3) * 4;
    float acc[4][4] = {};
    for (int k0 = 0; k0 < K; k0 += TK) {
        {
            int gr = row0 + lr;
            float4 v = make_float4(0.f, 0.f, 0.f, 0.f);
            if (gr < M) v = *(const float4*)(A + (size_t)gr * K + k0 + lc4);
            As[lc4 + 0][lr] = v.x; As[lc4 + 1][lr] = v.y;
            As[lc4 + 2][lr] = v.z; As[lc4 + 3][lr] = v.w;
        }
        {
            int n = tid & 63, kk0 = tid >> 6;
#pragma unroll
            for (int p = 0; p < 4; p++) {
                int kk = kk0 + p * 4;
                if (TRANSB) Bs[kk][n] = B[(size_t)(col0 + n) * K + k0 + kk];
                else        Bs[kk][n] = B[(size_t)(k0 + kk) * N + col0 + n];
            }
        }
        __syncthreads();
#pragma unroll
        for (int kk = 0; kk < TK; kk++) {
            float4 a = *(const float4*)&As[kk][ty * 4];
            float4 b = *(const float4*)&Bs[kk][tx * 4];
            float av[4] = {a.x, a.y, a.z, a.w};
            float bv[4] = {b.x, b.y, b.z, b.w};
#pragma unroll
            for (int i = 0; i < 4; i++)
#pragma unroll
                for (int j = 0; j < 4; j++) acc[i][j] += av[i] * bv[j];
        }
        __syncthreads();
    }
#pragma unroll
    for (int i = 0; i < 4; i++) {
        int r = row0 + ty * 4 + i;
        if (r >= M) continue;
#pragma unroll
        for (int j = 0; j < 4; j++) C[(size_t)r * N + col0 + tx * 4 + j] = acc[i][j];
    }
}

// ---------------- conversions ----------------
__global__ void k_cvt(const float* __restrict__ in, unsigned short* __restrict__ out, int n4) {
    int i = blockIdx.x * 256 + threadIdx.x;
    if (i >= n4) return;
    float4 v = ((const float4*)in)[i];
    ushort4 o;
    o.x = f2bf(v.x); o.y = f2bf(v.y); o.z = f2bf(v.z); o.w = f2bf(v.w);
    ((ushort4*)out)[i] = o;
}

// Pack Wsrc[512][256] f32 -> fragment layout chunks (see mfma_edge B-read mapping)
__device__ inline void packBF_task(const float* __restrict__ Wsrc,
                                   unsigned short* __restrict__ P, int blk) {
    int t = blk * 256 + threadIdx.x;
    int c = t >> 6, l = t & 63;
    int os = c >> 5, half = (c >> 4) & 1, colb = c & 15;
    int col = (colb << 4) + (l & 15);
    int k = (half << 8) + (os << 5) + ((l >> 4) << 3);
    bf16x8 v;
#pragma unroll
    for (int j = 0; j < 8; ++j) v[j] = (short)f2bf(Wsrc[(size_t)(k + j) * 256 + col]);
    *(bf16x8*)(P + (size_t)t * 8) = v;
}

// consolidated weight prep #1 (input-only deps): 1153 blocks
__global__ void k_prep1(const float* __restrict__ gc1W, const float* __restrict__ gc2W,
                        const float* __restrict__ msdrW, const float* __restrict__ wlin,
                        const float* __restrict__ blin, const float* __restrict__ mlw1,
                        const float* __restrict__ msw1,
                        unsigned short* __restrict__ gc1Wt, unsigned short* __restrict__ gc2Wt,
                        unsigned short* __restrict__ msdrWt, unsigned short* __restrict__ symb,
                        float* __restrict__ sumb, unsigned short* __restrict__ mlPk,
                        unsigned short* __restrict__ msPk) {
    __shared__ float s[256];
    int b = blockIdx.x, tid = threadIdx.x;
    if (b < 256) {
        int c = b;
        for (int r = tid; r < 256; r += 256) gc1Wt[c * 256 + r] = f2bf(gc1W[(size_t)r * 256 + c]);
    } else if (b < 512) {
        int c = b - 256;
        for (int r = tid; r < 256; r += 256) gc2Wt[c * 256 + r] = f2bf(gc2W[(size_t)r * 256 + c]);
    } else if (b < 768) {
        int c = b - 512;
        if (tid < 64) msdrWt[c * 64 + tid] = f2bf(msdrW[(size_t)tid * 256 + c]);
    } else if (b < 1024) {
        int r = b - 768, c = tid;
        symb[r * 256 + c] = f2bf(0.5f * (wlin[r * 256 + c] + wlin[c * 256 + r]));
    } else if (b == 1024) {
        s[tid] = blin[tid];
        __syncthreads();
        for (int o = 128; o > 0; o >>= 1) {
            if (tid < o) s[tid] += s[tid + o];
            __syncthreads();
        }
        if (tid == 0) sumb[0] = s[0];
    } else if (b < 1089) {
        packBF_task(mlw1, mlPk, b - 1025);
    } else {
        packBF_task(msw1, msPk, b - 1089);
    }
}
// consolidated weight prep #2 (after gemm_tiled): 768 blocks
__global__ void k_prep2(const float* __restrict__ Mqk, const float* __restrict__ linW,
                        const float* __restrict__ W2w, unsigned short* __restrict__ MqkT,
                        unsigned short* __restrict__ Bt) {
    int b = blockIdx.x, tid = threadIdx.x;
    if (b < 256) {
        int c = b;
        for (int r = tid; r < 256; r += 256) MqkT[c * 256 + r] = f2bf(Mqk[(size_t)r * 256 + c]);
    } else {
        int idx = (b - 256) * 256 + tid;
        int n = idx >> 9, k = idx & 511;
        float v = (k < 256) ? linW[(size_t)k * 256 + n] : W2w[(size_t)(k - 256) * 256 + n];
        Bt[idx] = f2bf(v);
    }
}

// ---------------- GCN aggregation: one wave per node, 4-deep neighbor prefetch ----------------
__global__ __launch_bounds__(256)
void k_agg_bf(const unsigned short* __restrict__ xw, const int* __restrict__ rowp,
              const int* __restrict__ csr, const float* __restrict__ dinv,
              const float* __restrict__ bias, unsigned short* __restrict__ out) {
    int w = threadIdx.x >> 6, lane = threadIdx.x & 63;
    int v = blockIdx.x * 4 + w;
    if (v >= Nn_) return;
    const uint2* x64 = (const uint2*)xw;
    // hoist self-row + bias loads (latency hides under the whole loop)
    uint2 us = x64[(size_t)v * 64 + lane];
    float dv = dinv[v];
    float4 bv = *(const float4*)(bias + lane * 4);
    float a0 = 0.f, a1 = 0.f, a2 = 0.f, a3 = 0.f;
    int beg = rowp[v], end = rowp[v + 1];
    uint2 u0 = make_uint2(0, 0), u1 = make_uint2(0, 0);
    uint2 u2 = make_uint2(0, 0), u3 = make_uint2(0, 0);
    float e0 = 0.f, e1 = 0.f, e2 = 0.f, e3 = 0.f;
    if (beg < end)     { int s = csr[beg];     e0 = dinv[s]; u0 = x64[(size_t)s * 64 + lane]; }
    if (beg + 1 < end) { int s = csr[beg + 1]; e1 = dinv[s]; u1 = x64[(size_t)s * 64 + lane]; }
    if (beg + 2 < end) { int s = csr[beg + 2]; e2 = dinv[s]; u2 = x64[(size_t)s * 64 + lane]; }
    if (beg + 3 < end) { int s = csr[beg + 3]; e3 = dinv[s]; u3 = x64[(size_t)s * 64 + lane]; }
    #pragma unroll 4
    for (int p = beg; p < end; ++p) {
        uint2 uc = u0; float dc = e0;
        u0 = u1; e0 = e1;
        u1 = u2; e1 = e2;
        u2 = u3; e2 = e3;
        if (p + 4 < end) {
            int s = csr[p + 4];
            e3 = dinv[s];
            u3 = x64[(size_t)s * 64 + lane];
        }
        a0 += bf2f(uc.x & 0xffff) * dc;
        a1 += bf2f(uc.x >> 16) * dc;
        a2 += bf2f(uc.y & 0xffff) * dc;
        a3 += bf2f(uc.y >> 16) * dc;
    }
    a0 = a0 * dv + bf2f(us.x & 0xffff) * dv * dv;
    a1 = a1 * dv + bf2f(us.x >> 16) * dv * dv;
    a2 = a2 * dv + bf2f(us.y & 0xffff) * dv * dv;
    a3 = a3 * dv + bf2f(us.y >> 16) * dv * dv;
    uint2 ov;
    ov.x = (unsigned int)f2bf(tanh_fast(a0 + bv.x)) |
           ((unsigned int)f2bf(tanh_fast(a1 + bv.y)) << 16);
    ov.y = (unsigned int)f2bf(tanh_fast(a2 + bv.z)) |
           ((unsigned int)f2bf(tanh_fast(a3 + bv.w)) << 16);
    ((uint2*)out)[(size_t)v * 64 + lane] = ov;
}

// ---------------- MFMA GEMM, dbuf LDS + raw barriers + counted vmcnt ----------------
template <bool BIAS, bool TANH>
__global__ __launch_bounds__(256)
void mfma_gemm(const unsigned short* __restrict__ A0, const unsigned short* __restrict__ A1,
               int Ksplit, int K, const unsigned short* __restrict__ Bt,
               const float* __restrict__ bias, unsigned short* __restrict__ Cb, int M) {
    __shared__ char lds[2][16384];
    int tid = threadIdx.x, lane = tid & 63, w = tid >> 6;
    int row0 = blockIdx.y * 128, col0 = blockIdx.x * 128;
    int wr = w >> 1, wc = w & 1;
    f32x4 acc[4][4] = {};
    int nk = K >> 5;

    auto stage = [&](int ks, int buf) {
        int k0 = ks << 5;
        #pragma unroll
        for (int j = 0; j < 4; ++j) {
            int ins = w + (j << 2);
            int lrow = ((ins & 7) << 4) + (lane >> 2);
            int p = lane & 3;
            int slog = p ^ ((lrow >> 1) & 3);
            char* ldst = lds[buf] + ((ins & 7) << 10) + ((ins >= 8) ? 8192 : 0);
            const unsigned short* src;
            if (ins < 8) {
                int grow = row0 + lrow;
                if (grow >= M) grow = M - 1;
                const unsigned short* Asrc; int kk, pitch;
                if (k0 < Ksplit) { Asrc = A0; kk = k0; pitch = Ksplit; }
                else             { Asrc = A1; kk = k0 - Ksplit; pitch = K - Ksplit; }
                src = Asrc + (size_t)grow * pitch + kk + (slog << 3);
            } else {
                int grow = col0 + lrow;
                src = Bt + (size_t)grow * K + k0 + (slog << 3);
            }
            gload_lds16(src, ldst);
        }
    };

    stage(0, 0);
    for (int ks = 0; ks < nk; ++ks) {
        int cur = ks & 1;
        if (ks + 1 < nk) {
            stage(ks + 1, cur ^ 1);
            asm volatile("s_waitcnt vmcnt(4)" ::: "memory");
        } else {
            asm volatile("s_waitcnt vmcnt(0)" ::: "memory");
        }
        __builtin_amdgcn_s_barrier();
        __builtin_amdgcn_sched_barrier(0);
        int s = lane >> 4, r16 = lane & 15;
        bf16x8 a[4], b[4];
        #pragma unroll
        for (int m = 0; m < 4; ++m) a[m] = *(const bf16x8*)(lds[cur] + lds_off(wr * 64 + m * 16 + r16, s));
        #pragma unroll
        for (int n = 0; n < 4; ++n) b[n] = *(const bf16x8*)(lds[cur] + 8192 + lds_off(wc * 64 + n * 16 + r16, s));
        __builtin_amdgcn_s_setprio(1);
        #pragma unroll
        for (int m = 0; m < 4; ++m)
            #pragma unroll
            for (int n = 0; n < 4; ++n)
                acc[m][n] = __builtin_amdgcn_mfma_f32_16x16x32_bf16(a[m], b[n], acc[m][n], 0, 0, 0);
        __builtin_amdgcn_s_setprio(0);
        __builtin_amdgcn_s_barrier();
        __builtin_amdgcn_sched_barrier(0);
    }
    int q = lane >> 4, r16 = lane & 15;
    float bv[4];
    #pragma unroll
    for (int n = 0; n < 4; ++n) bv[n] = BIAS ? bias[col0 + wc * 64 + n * 16 + r16] : 0.f;
    #pragma unroll
    for (int m = 0; m < 4; ++m) {
        #pragma unroll
        for (int i = 0; i < 4; ++i) {
            int row = row0 + wr * 64 + m * 16 + q * 4 + i;
            if (row >= M) continue;
            #pragma unroll
            for (int n = 0; n < 4; ++n) {
                int col = col0 + wc * 64 + n * 16 + r16;
                float v = acc[m][n][i];
                if (BIAS) v += bv[n];
                if (TANH) v = tanh_fast(v);
                Cb[(size_t)row * 256 + col] = f2bf(v);
            }
        }
    }
}

// ---------------- attention u: 16 lanes/node, online softmax ----------------
__global__ __launch_bounds__(256)
void k_attn_u2(const unsigned short* __restrict__ emb, const unsigned short* __restrict__ t,
               const float* __restrict__ p0, const float* __restrict__ p1,
               const float* __restrict__ p2, unsigned short* __restrict__ u) {
    int tid = threadIdx.x;
    int g = tid >> 4, l = tid & 15;
    int n = blockIdx.x * 16 + g;
    size_t eoff = (size_t)n * 256 + l * 16;
    const uint4* e16 = (const uint4*)(emb + eoff);
    uint4* u16 = (uint4*)(u + eoff);
    uint4 eb0 = e16[0], eb1 = e16[1];
    if (n >= P2_) { u16[0] = eb0; u16[1] = eb1; return; }
    float tv[16], ev[16];
    {
        const uint4* t16 = (const uint4*)(t + eoff);
        unpk8(t16[0], tv); unpk8(t16[1], tv + 8);
        unpk8(eb0, ev); unpk8(eb1, ev + 8);
    }
    float m = -3.0e38f, den = 0.f, o[16];
    #pragma unroll
    for (int i = 0; i < 16; i++) o[i] = 0.f;
    auto accum = [&](const float* sv) {
        float dt = 0.f;
        #pragma unroll
        for (int i = 0; i < 16; i++) dt += tv[i] * sv[i];
        dt += __shfl_xor(dt, 1);
        dt += __shfl_xor(dt, 2);
        dt += __shfl_xor(dt, 4);
        dt += __shfl_xor(dt, 8);
        float lg = dt * 0.0625f;
        float mn = fmaxf(m, lg);
        float s0 = __expf(m - mn), s1 = __expf(lg - mn);
        den = den * s0 + s1;
        #pragma unroll
        for (int i = 0; i < 16; i++) o[i] = o[i] * s0 + s1 * sv[i];
        m = mn;
    };
    auto accum_f32 = [&](const float* base) {
        float sv[16];
        const float4* b4 = (const float4*)(base + eoff);
        #pragma unroll
        for (int i = 0; i < 4; i++) {
            float4 q = b4[i];
            sv[4 * i] = q.x; sv[4 * i + 1] = q.y; sv[4 * i + 2] = q.z; sv[4 * i + 3] = q.w;
        }
        accum(sv);
    };
    if (n < P0_)      { accum_f32(p0); accum_f32(p1); accum_f32(p2); }
    else if (n < P1_) { accum_f32(p1); accum_f32(p2); }
    else              { accum_f32(p2); }
    accum(ev);
    float inv = __builtin_amdgcn_rcpf(den);
    unsigned short h[16];
    #pragma unroll
    for (int i = 0; i < 16; i++) h[i] = f2bf(o[i] * inv);
    uint4 r0, r1;
    r0.x = h[0] | ((unsigned int)h[1] << 16);  r0.y = h[2] | ((unsigned int)h[3] << 16);
    r0.z = h[4] | ((unsigned int)h[5] << 16);  r0.w = h[6] | ((unsigned int)h[7] << 16);
    r1.x = h[8] | ((unsigned int)h[9] << 16);  r1.y = h[10] | ((unsigned int)h[11] << 16);
    r1.z = h[12] | ((unsigned int)h[13] << 16); r1.w = h[14] | ((unsigned int)h[15] << 16);
    u16[0] = r0; u16[1] = r1;
}

// ---------------- fused edge MLP v3': 256 thr, 64 edges, B direct-to-reg, both halves before prefetch ----------------
template <bool SIM>
__global__ __launch_bounds__(256)
void mfma_edge3(const unsigned short* __restrict__ srcemb, const unsigned short* __restrict__ gsrc,
                const int* __restrict__ es, const int* __restrict__ ed,
                const unsigned short* __restrict__ PkF, const float* __restrict__ b1,
                const float* __restrict__ w2, const float* __restrict__ sumb,
                float* __restrict__ a_pre, float* __restrict__ mlsc) {
    __shared__ char lds[8192];    // A: mean 4K | max 4K
    __shared__ float red[64];
    int tid = threadIdx.x, lane = tid & 63, w = tid >> 6;
    int e0 = blockIdx.x * 64;
    int arow = tid >> 2, p = tid & 3;
    int ia = es[e0 + arow], ib = ed[e0 + arow];
    const unsigned short* ra = srcemb + (size_t)ia * 256;
    const unsigned short* rb = srcemb + (size_t)ib * 256;
    const unsigned short* rg = SIM ? (gsrc + (size_t)ia * 256) : nullptr;
    int slog = p ^ ((arow >> 1) & 3);
    int abase = arow * 64 + (p << 4);
    if (tid < 64) red[tid] = 0.f;
    float simacc = 0.f;
    f32x4 acc[4][4] = {};
    // prologue: prefetch step-0 A slices into registers
    uint4 pa = *(const uint4*)(ra + (slog << 3));
    uint4 pb = *(const uint4*)(rb + (slog << 3));
    uint4 pg = make_uint4(0, 0, 0, 0);
    if (SIM) pg = *(const uint4*)(rg + (slog << 3));
    const bf16x8* BF = (const bf16x8*)PkF;   // chunk c: BF[c*64 + lane]
    for (int os = 0; os < 8; ++os) {
        // A convert + swizzled ds_write (compiler waits on pa/pb/pg)
        {
            unsigned int m0, x0, m1, x1, m2, x2, m3, x3;
            meanmax_u(pa.x, pb.x, m0, x0);
            meanmax_u(pa.y, pb.y, m1, x1);
            meanmax_u(pa.z, pb.z, m2, x2);
            meanmax_u(pa.w, pb.w, m3, x3);
            *(uint4*)(lds + abase) = make_uint4(m0, m1, m2, m3);
            *(uint4*)(lds + 4096 + abase) = make_uint4(x0, x1, x2, x3);
            if (SIM)
                simacc += dot2_u(pg.x, pb.x) + dot2_u(pg.y, pb.y) +
                          dot2_u(pg.z, pb.z) + dot2_u(pg.w, pb.w);
        }
        // BOTH B-half fragments loaded BEFORE the A-prefetch (vmcnt is FIFO:
        // loads issued after the prefetch would force it to drain at the MFMA wait)
        bf16x8 b0[4], b1f[4];
        #pragma unroll
        for (int n2 = 0; n2 < 4; ++n2) {
            int c0i = (os << 5) + (w << 2) + n2;
            b0[n2]  = BF[(size_t)c0i * 64 + lane];
            b1f[n2] = BF[(size_t)(c0i + 16) * 64 + lane];
        }
        // A prefetch for step os+1 (newest loads -> stay in flight across whole step)
        if (os < 7) {
            int cb = ((os + 1) << 5) + (slog << 3);
            pa = *(const uint4*)(ra + cb);
            pb = *(const uint4*)(rb + cb);
            if (SIM) pg = *(const uint4*)(rg + cb);
        }
        asm volatile("s_waitcnt lgkmcnt(0)" ::: "memory");   // A ds_writes visible
        __builtin_amdgcn_s_barrier();
        __builtin_amdgcn_sched_barrier(0);
        int s = lane >> 4, r16 = lane & 15;
        {
            bf16x8 a[4];
            #pragma unroll
            for (int m2 = 0; m2 < 4; ++m2)
                a[m2] = *(const bf16x8*)(lds + lds_off(m2 * 16 + r16, s));
            __builtin_amdgcn_s_setprio(1);
            #pragma unroll
            for (int m2 = 0; m2 < 4; ++m2)
                #pragma unroll
                for (int n2 = 0; n2 < 4; ++n2)
                    acc[m2][n2] = __builtin_amdgcn_mfma_f32_16x16x32_bf16(a[m2], b0[n2], acc[m2][n2], 0, 0, 0);
            __builtin_amdgcn_s_setprio(0);
        }
        {
            bf16x8 a[4];
            #pragma unroll
            for (int m2 = 0; m2 < 4; ++m2)
                a[m2] = *(const bf16x8*)(lds + 4096 + lds_off(m2 * 16 + r16, s));
            __builtin_amdgcn_s_setprio(1);
            #pragma unroll
            for (int m2 = 0; m2 < 4; ++m2)
                #pragma unroll
                for (int n2 = 0; n2 < 4; ++n2)
                    acc[m2][n2] = __builtin_amdgcn_mfma_f32_16x16x32_bf16(a[m2], b1f[n2], acc[m2][n2], 0, 0, 0);
            __builtin_amdgcn_s_setprio(0);
        }
        __builtin_amdgcn_s_barrier();
        __builtin_amdgcn_sched_barrier(0);
    }
    // epilogue: layer-2 dot, reduce to per-edge scalar
    int q = lane >> 4, r16 = lane & 15;
    float b1c[4], w2c[4];
    #pragma unroll
    for (int n2 = 0; n2 < 4; ++n2) {
        int c = (w << 6) + n2 * 16 + r16;
        b1c[n2] = b1[c]; w2c[n2] = w2[c];
    }
    #pragma unroll
    for (int m2 = 0; m2 < 4; ++m2) {
        #pragma unroll
        for (int i = 0; i < 4; ++i) {
            int row = m2 * 16 + q * 4 + i;
            float ps = 0.f;
            #pragma unroll
            for (int n2 = 0; n2 < 4; ++n2) ps += tanh_fast(acc[m2][n2][i] + b1c[n2]) * w2c[n2];
            ps += __shfl_xor(ps, 1);
            ps += __shfl_xor(ps, 2);
            ps += __shfl_xor(ps, 4);
            ps += __shfl_xor(ps, 8);
            if (r16 == 0) atomicAdd(&red[row], ps);
        }
    }
    if (SIM) {
        simacc += __shfl_xor(simacc, 1);
        simacc += __shfl_xor(simacc, 2);
        if (p == 0) mlsc[e0 + arow] = sigmoid_fast(simacc + sumb[0]);
    }
    __syncthreads();
    if (tid < 64) a_pre[e0 + tid] = red[tid];
}

// ---------------- final ensemble ----------------
__global__ void k_final(const float* __restrict__ apml, const float* __restrict__ apms,
                        const float* __restrict__ mlsc, const float* __restrict__ mstr,
                        const float* __restrict__ pxtr, const int* __restrict__ index,
                        const float* __restrict__ mlb2, const float* __restrict__ msb2,
                        float* __restrict__ out) {
    int e = blockIdx.x * 256 + threadIdx.x;
    if (e >= E_) return;
    float aml = tanh_fast(apml[e] + mlb2[0]);
    float ams = tanh_fast(apms[e] + msb2[0]);
    float apx = PROXW;
    float m = fmaxf(aml, fmaxf(ams, apx));
    float wml = __expf(aml - m), wms = __expf(ams - m), wpx = __expf(apx - m);
    float inv = __builtin_amdgcn_rcpf(wml + wms + wpx);
    int idx = index[e];
    float v = (mlsc[e] * wml + mstr[idx] * wms + pxtr[idx] * wpx) * inv;
    out[e] = fminf(fmaxf(v, 0.f), 1.f);
}

__global__ void k_sentinel(float* out, int n) {
    int i = blockIdx.x * 256 + threadIdx.x;
    if (i < n) out[i] = -12345.0f;
}

// ---------------- launch ----------------
extern "C" void kernel_launch(void* const* d_in, const int* in_sizes, int n_in,
                              void* d_out, int out_size, void* d_ws, size_t ws_size,
                              hipStream_t stream) {
    const float* x     = (const float*)d_in[0];
    const int*   mp    = (const int*)d_in[1];
    const int*   edges = (const int*)d_in[2];
    const int*   index = (const int*)d_in[3];
    const float* p0    = (const float*)d_in[4];
    const float* p1    = (const float*)d_in[5];
    const float* p2    = (const float*)d_in[6];
    const float* gc1W  = (const float*)d_in[7];
    const float* gc1b  = (const float*)d_in[8];
    const float* gc2W  = (const float*)d_in[9];
    const float* gc2b  = (const float*)d_in[10];
    const float* linW  = (const float*)d_in[11];
    const float* linb  = (const float*)d_in[12];
    const float* wlin  = (const float*)d_in[13];
    const float* blin  = (const float*)d_in[14];
    const float* wq    = (const float*)d_in[15];
    const float* wk    = (const float*)d_in[16];
    const float* wv    = (const float*)d_in[17];
    const float* mlw1  = (const float*)d_in[18];
    const float* mlb1  = (const float*)d_in[19];
    const float* mlw2  = (const float*)d_in[20];
    const float* mlb2  = (const float*)d_in[21];
    const float* msw1  = (const float*)d_in[22];
    const float* msb1  = (const float*)d_in[23];
    const float* msw2  = (const float*)d_in[24];
    const float* msb2  = (const float*)d_in[25];
    const float* msdrW = (const float*)d_in[26];
    const float* msdrb = (const float*)d_in[27];
    const float* logits = (const float*)d_in[28];
    const float* mstr  = (const float*)d_in[29];
    const float* pxtr  = (const float*)d_in[30];
    float* out = (float*)d_out;

    const int* src_mp = mp;
    const int* dst_mp = mp + EMP_;
    const int* es = edges;
    const int* ed = edges + E_;

    char* ws = (char*)d_ws;
    size_t off = 0;
    auto alloc = [&](size_t bytes) -> char* {
        off = (off + 255) & ~(size_t)255;
        char* r = ws + off;
        off += bytes;
        return r;
    };
    const size_t NODE_BF = (size_t)Nn_ * 256 * 2;
    unsigned short* W0 = (unsigned short*)alloc(NODE_BF);  // xb -> gb
    unsigned short* W1 = (unsigned short*)alloc(NODE_BF);  // xw1/xw2 -> logitsb
    unsigned short* W2 = (unsigned short*)alloc(NODE_BF);  // hb -> rb
    unsigned short* W3 = (unsigned short*)alloc(NODE_BF);  // embb
    unsigned short* W4 = (unsigned short*)alloc(NODE_BF);  // tb/ub
    unsigned short* W5 = (unsigned short*)alloc(NODE_BF);  // emb2b
    int*   cnt  = (int*)alloc((size_t)Nn_ * 4);
    int*   rowp = (int*)alloc((size_t)(Nn_ + 1) * 4);
    int*   fill = (int*)alloc((size_t)Nn_ * 4);
    int*   csr  = (int*)alloc((size_t)EMP_ * 4);
    float* dinv = (float*)alloc((size_t)Nn_ * 4);
    int*   bsum = (int*)alloc(512 * 4);
    float* Mqk  = (float*)alloc(65536 * 4);
    float* W2wf = (float*)alloc(65536 * 4);
    unsigned short* gc1Wt = (unsigned short*)alloc(65536 * 2);
    unsigned short* gc2Wt = (unsigned short*)alloc(65536 * 2);
    unsigned short* MqkT  = (unsigned short*)alloc(65536 * 2);
    unsigned short* Bt512 = (unsigned short*)alloc(131072 * 2);
    unsigned short* symb  = (unsigned short*)alloc(65536 * 2);
    unsigned short* msdrWt = (unsigned short*)alloc(16384 * 2);
    unsigned short* mlPk  = (unsigned short*)alloc(131072 * 2);
    unsigned short* msPk  = (unsigned short*)alloc(131072 * 2);
    float* apml = (float*)alloc((size_t)E_ * 4);
    float* apms = (float*)alloc((size_t)E_ * 4);
    float* mlsc = (float*)alloc((size_t)E_ * 4);
    float* sumb = (float*)alloc(256);

    if (off > ws_size) {
        k_sentinel<<<(E_ + 255) / 256, 256, 0, stream>>>(out, E_);
        return;
    }

    hipMemsetAsync(cnt, 0, (size_t)Nn_ * 4, stream);
    hipMemsetAsync(fill, 0, (size_t)Nn_ * 4, stream);

    const int NB = (Nn_ + 255) / 256;
    const int EB = (EMP_ + 255) / 256;

    // input conversions + consolidated weight prep
    k_cvt<<<30000, 256, 0, stream>>>(x, W0, Nn_ * 256 / 4);
    k_prep1<<<1153, 256, 0, stream>>>(gc1W, gc2W, msdrW, wlin, blin, mlw1, msw1,
                                      gc1Wt, gc2Wt, msdrWt, symb, sumb, mlPk, msPk);
    dim3 gSmall(4, 4);
    gemm_tiled<true><<<gSmall, 256, 0, stream>>>(wq, wk, Mqk, 256, 256, 256);
    gemm_tiled<false><<<gSmall, 256, 0, stream>>>(wv, linW + 256 * 256, W2wf, 256, 256, 256);
    k_prep2<<<768, 256, 0, stream>>>(Mqk, linW, W2wf, MqkT, Bt512);

    // CSR
    k_count<<<EB, 256, 0, stream>>>(dst_mp, cnt, EMP_);
    k_block_reduce<<<NB, 256, 0, stream>>>(cnt, bsum, Nn_);
    k_scan_bsum<<<1, 64, 0, stream>>>(bsum, NB);
    k_scan_final<<<NB, 256, 0, stream>>>(cnt, bsum, rowp, Nn_, EMP_);
    k_fill<<<EB, 256, 0, stream>>>(src_mp, dst_mp, rowp, fill, csr, EMP_);
    k_dinv<<<NB, 256, 0, stream>>>(cnt, dinv, Nn_);

    dim3 gFull(2, (Nn_ + 127) / 128);
    dim3 gT(2, (P2_ + 127) / 128);
    const int AGG_B = (Nn_ + 3) / 4;

    // GCN layer 1
    mfma_gemm<false, false><<<gFull, 256, 0, stream>>>(W0, W0, 256, 256, gc1Wt, nullptr, W1, Nn_);
    k_agg_bf<<<AGG_B, 256, 0, stream>>>(W1, rowp, csr, dinv, gc1b, W2);
    // GCN layer 2
    mfma_gemm<false, false><<<gFull, 256, 0, stream>>>(W2, W2, 256, 256, gc2Wt, nullptr, W1, Nn_);
    k_agg_bf<<<AGG_B, 256, 0, stream>>>(W1, rowp, csr, dinv, gc2b, W3);

    // attention: t = emb @ Mqk (rows < P2), then u (16 nodes/block)
    mfma_gemm<false, false><<<gT, 256, 0, stream>>>(W3, W3, 256, 256, MqkT, nullptr, W4, P2_);
    k_attn_u2<<<Nn_ / 16, 256, 0, stream>>>(W3, W4, p0, p1, p2, W4);

    // emb2 = tanh([emb|u] @ Bt512^T + linb)
    mfma_gemm<true, true><<<gFull, 256, 0, stream>>>(W3, W4, 256, 512, Bt512, linb, W5, Nn_);

    // g = emb2 @ sym
    mfma_gemm<false, false><<<gFull, 256, 0, stream>>>(W5, W5, 256, 256, symb, nullptr, W0, Nn_);

    // r = tanh(logits @ msdrW + msdrb)
    k_cvt<<<7500, 256, 0, stream>>>(logits, W1, Nn_ * 64 / 4);
    mfma_gemm<true, true><<<gFull, 256, 0, stream>>>(W1, W1, 64, 64, msdrWt, msdrb, W2, Nn_);

    // edge MLPs (+fused bilinear sim in the ml pass)
    mfma_edge3<true><<<E_ / 64, 256, 0, stream>>>(W5, W0, es, ed, mlPk, mlb1, mlw2, sumb, apml, mlsc);
    mfma_edge3<false><<<E_ / 64, 256, 0, stream>>>(W2, nullptr, es, ed, msPk, msb1, msw2, sumb, apms, nullptr);

    // final ensemble
    k_final<<<(E_ + 255) / 256, 256, 0, stream>>>(apml, apms, mlsc, mstr, pxtr, index, mlb2, msb2, out);
}

// Round 12
// 929.152 us; speedup vs baseline: 1.1940x; 1.0189x over previous
//
#include <hip/hip_runtime.h>
#include <hip/hip_bf16.h>

// ---------------- constants ----------------
#define Nn_   120000
#define F_    256
#define H_    256
#define L_    64
#define EMP_  1000000
#define E_    200000
#define P0_   60000
#define P1_   80000
#define P2_   100000
#define PROXW 0.3f

typedef __attribute__((ext_vector_type(8))) short bf16x8;
typedef __attribute__((ext_vector_type(4))) float f32x4;

__device__ inline float bf2f(unsigned short u) {
    union { unsigned int i; float f; } x; x.i = ((unsigned int)u) << 16; return x.f;
}
__device__ inline unsigned short f2bf(float f) {
    union { float f; unsigned int i; } x; x.f = f;
    unsigned int r = x.i + 0x7fffu + ((x.i >> 16) & 1u);
    return (unsigned short)(r >> 16);
}
__device__ inline float tanh_fast(float x) {
    float e = __expf(2.0f * x);
    return 1.0f - 2.0f * __builtin_amdgcn_rcpf(e + 1.0f);
}
__device__ inline float sigmoid_fast(float z) {
    return __builtin_amdgcn_rcpf(1.0f + __expf(-z));
}
__device__ inline int lds_off(int row, int s) {
    return row * 64 + ((s ^ ((row >> 1) & 3)) << 4);
}
__device__ inline void gload_lds16(const void* g, void* l) {
    __builtin_amdgcn_global_load_lds((const __attribute__((address_space(1))) void*)g,
                                     (__attribute__((address_space(3))) void*)l, 16, 0, 0);
}
__device__ inline void unpk8(uint4 u, float* o) {
    o[0] = bf2f(u.x & 0xffff); o[1] = bf2f(u.x >> 16);
    o[2] = bf2f(u.y & 0xffff); o[3] = bf2f(u.y >> 16);
    o[4] = bf2f(u.z & 0xffff); o[5] = bf2f(u.z >> 16);
    o[6] = bf2f(u.w & 0xffff); o[7] = bf2f(u.w >> 16);
}
// mean & max of two packed bf16 pairs; max needs no re-rounding
__device__ inline void meanmax_u(unsigned int ua, unsigned int ub,
                                 unsigned int& um, unsigned int& ux) {
    float alo = __uint_as_float(ua << 16);
    float ahi = __uint_as_float(ua & 0xffff0000u);
    float blo = __uint_as_float(ub << 16);
    float bhi = __uint_as_float(ub & 0xffff0000u);
    um = (unsigned int)f2bf((alo + blo) * 0.5f) |
         ((unsigned int)f2bf((ahi + bhi) * 0.5f) << 16);
    ux = (__float_as_uint(fmaxf(alo, blo)) >> 16) |
         (__float_as_uint(fmaxf(ahi, bhi)) & 0xffff0000u);
}
__device__ inline float dot2_u(unsigned int ug, unsigned int ub) {
    float gl = __uint_as_float(ug << 16);
    float gh = __uint_as_float(ug & 0xffff0000u);
    float bl = __uint_as_float(ub << 16);
    float bh = __uint_as_float(ub & 0xffff0000u);
    return fmaf(gl, bl, gh * bh);
}

// ---------------- CSR build ----------------
__global__ void k_count(const int* __restrict__ dst, int* __restrict__ cnt, int n) {
    int e = blockIdx.x * 256 + threadIdx.x;
    if (e < n) atomicAdd(&cnt[dst[e]], 1);
}
__global__ void k_block_reduce(const int* __restrict__ cnt, int* __restrict__ bsum, int n) {
    __shared__ int s[256];
    int i = blockIdx.x * 256 + threadIdx.x;
    s[threadIdx.x] = (i < n) ? cnt[i] : 0;
    __syncthreads();
    for (int o = 128; o > 0; o >>= 1) {
        if (threadIdx.x < o) s[threadIdx.x] += s[threadIdx.x + o];
        __syncthreads();
    }
    if (threadIdx.x == 0) bsum[blockIdx.x] = s[0];
}
__global__ void k_scan_bsum(int* bsum, int nb) {
    if (threadIdx.x == 0 && blockIdx.x == 0) {
        int acc = 0;
        for (int i = 0; i < nb; i++) { int v = bsum[i]; bsum[i] = acc; acc += v; }
    }
}
__global__ void k_scan_final(const int* __restrict__ cnt, const int* __restrict__ bsum,
                             int* __restrict__ rowp, int n, int etot) {
    __shared__ int s[256];
    int tid = threadIdx.x;
    int i = blockIdx.x * 256 + tid;
    int v = (i < n) ? cnt[i] : 0;
    s[tid] = v;
    __syncthreads();
    for (int o = 1; o < 256; o <<= 1) {
        int t = 0;
        if (tid >= o) t = s[tid - o];
        __syncthreads();
        s[tid] += t;
        __syncthreads();
    }
    if (i < n) rowp[i] = bsum[blockIdx.x] + s[tid] - v;
    if (i == 0 && blockIdx.x == 0) rowp[n] = etot;
}
__global__ void k_fill(const int* __restrict__ src, const int* __restrict__ dst,
                       const int* __restrict__ rowp, int* __restrict__ fill,
                       int* __restrict__ csr, int n) {
    int e = blockIdx.x * 256 + threadIdx.x;
    if (e < n) {
        int d = dst[e];
        int p = atomicAdd(&fill[d], 1);
        csr[rowp[d] + p] = src[e];
    }
}
__global__ void k_dinv(const int* __restrict__ cnt, float* __restrict__ dinv, int n) {
    int i = blockIdx.x * 256 + threadIdx.x;
    if (i < n) dinv[i] = rsqrtf((float)cnt[i] + 1.0f);
}

// ---------------- small f32 tiled GEMM (256^3 precomputes only) ----------------
#define TM 64
#define TN 64
#define TK 16
template <bool TRANSB>
__global__ void gemm_tiled(const float* __restrict__ A, const float* __restrict__ B,
                           float* __restrict__ C, int M, int K, int N) {
    __shared__ float As[TK][TM + 4];
    __shared__ float Bs[TK][TN + 4];
    int tid = threadIdx.x;
    int tx = tid & 15, ty = tid >> 4;
    int row0 = blockIdx.y * TM, col0 = blockIdx.x * TN;
    int lr = tid >> 2, lc4 = (tid & 3) * 4;
    float acc[4][4] = {};
    for (int k0 = 0; k0 < K; k0 += TK) {
        {
            int gr = row0 + lr;
            float4 v = make_float4(0.f, 0.f, 0.f, 0.f);
            if (gr < M) v = *(const float4*)(A + (size_t)gr * K + k0 + lc4);
            As[lc4 + 0][lr] = v.x; As[lc4 + 1][lr] = v.y;
            As[lc4 + 2][lr] = v.z; As[lc4 + 3][lr] = v.w;
        }
        {
            int n = tid & 63, kk0 = tid >> 6;
#pragma unroll
            for (int p = 0; p < 4; p++) {
                int kk = kk0 + p * 4;
                if (TRANSB) Bs[kk][n] = B[(size_t)(col0 + n) * K + k0 + kk];
                else        Bs[kk][n] = B[(size_t)(k0 + kk) * N + col0 + n];
            }
        }
        __syncthreads();
#pragma unroll
        for (int kk = 0; kk < TK; kk++) {
            float4 a = *(const float4*)&As[kk][ty * 4];
            float4 b = *(const float4*)&Bs[kk][tx * 4];
            float av[4] = {a.x, a.y, a.z, a.w};
            float bv[4] = {b.x, b.y, b.z, b.w};
#pragma unroll
            for (int i = 0; i < 4; i++)
#pragma unroll
                for (int j = 0; j < 4; j++) acc[i][j] += av[i] * bv[j];
        }
        __syncthreads();
    }
#pragma unroll
    for (int i = 0; i < 4; i++) {
        int r = row0 + ty * 4 + i;
        if (r >= M) continue;
#pragma unroll
        for (int j = 0; j < 4; j++) C[(size_t)r * N + col0 + tx * 4 + j] = acc[i][j];
    }
}

// ---------------- conversions ----------------
__global__ void k_cvt(const float* __restrict__ in, unsigned short* __restrict__ out, int n4) {
    int i = blockIdx.x * 256 + threadIdx.x;
    if (i >= n4) return;
    float4 v = ((const float4*)in)[i];
    ushort4 o;
    o.x = f2bf(v.x); o.y = f2bf(v.y); o.z = f2bf(v.z); o.w = f2bf(v.w);
    ((ushort4*)out)[i] = o;
}

// Pack Wsrc[512][256] f32 -> fragment layout chunks (see mfma_edge B-read mapping)
__device__ inline void packBF_task(const float* __restrict__ Wsrc,
                                   unsigned short* __restrict__ P, int blk) {
    int t = blk * 256 + threadIdx.x;
    int c = t >> 6, l = t & 63;
    int os = c >> 5, half = (c >> 4) & 1, colb = c & 15;
    int col = (colb << 4) + (l & 15);
    int k = (half << 8) + (os << 5) + ((l >> 4) << 3);
    bf16x8 v;
#pragma unroll
    for (int j = 0; j < 8; ++j) v[j] = (short)f2bf(Wsrc[(size_t)(k + j) * 256 + col]);
    *(bf16x8*)(P + (size_t)t * 8) = v;
}

// consolidated weight prep #1 (input-only deps): 1153 blocks
__global__ void k_prep1(const float* __restrict__ gc1W, const float* __restrict__ gc2W,
                        const float* __restrict__ msdrW, const float* __restrict__ wlin,
                        const float* __restrict__ blin, const float* __restrict__ mlw1,
                        const float* __restrict__ msw1,
                        unsigned short* __restrict__ gc1Wt, unsigned short* __restrict__ gc2Wt,
                        unsigned short* __restrict__ msdrWt, unsigned short* __restrict__ symb,
                        float* __restrict__ sumb, unsigned short* __restrict__ mlPk,
                        unsigned short* __restrict__ msPk) {
    __shared__ float s[256];
    int b = blockIdx.x, tid = threadIdx.x;
    if (b < 256) {
        int c = b;
        for (int r = tid; r < 256; r += 256) gc1Wt[c * 256 + r] = f2bf(gc1W[(size_t)r * 256 + c]);
    } else if (b < 512) {
        int c = b - 256;
        for (int r = tid; r < 256; r += 256) gc2Wt[c * 256 + r] = f2bf(gc2W[(size_t)r * 256 + c]);
    } else if (b < 768) {
        int c = b - 512;
        if (tid < 64) msdrWt[c * 64 + tid] = f2bf(msdrW[(size_t)tid * 256 + c]);
    } else if (b < 1024) {
        int r = b - 768, c = tid;
        symb[r * 256 + c] = f2bf(0.5f * (wlin[r * 256 + c] + wlin[c * 256 + r]));
    } else if (b == 1024) {
        s[tid] = blin[tid];
        __syncthreads();
        for (int o = 128; o > 0; o >>= 1) {
            if (tid < o) s[tid] += s[tid + o];
            __syncthreads();
        }
        if (tid == 0) sumb[0] = s[0];
    } else if (b < 1089) {
        packBF_task(mlw1, mlPk, b - 1025);
    } else {
        packBF_task(msw1, msPk, b - 1089);
    }
}
// consolidated weight prep #2 (after gemm_tiled): 768 blocks
__global__ void k_prep2(const float* __restrict__ Mqk, const float* __restrict__ linW,
                        const float* __restrict__ W2w, unsigned short* __restrict__ MqkT,
                        unsigned short* __restrict__ Bt) {
    int b = blockIdx.x, tid = threadIdx.x;
    if (b < 256) {
        int c = b;
        for (int r = tid; r < 256; r += 256) MqkT[c * 256 + r] = f2bf(Mqk[(size_t)r * 256 + c]);
    } else {
        int idx = (b - 256) * 256 + tid;
        int n = idx >> 9, k = idx & 511;
        float v = (k < 256) ? linW[(size_t)k * 256 + n] : W2w[(size_t)(k - 256) * 256 + n];
        Bt[idx] = f2bf(v);
    }
}

// ---------------- GCN aggregation: one wave per node, 4-deep neighbor prefetch ----------------
__global__ __launch_bounds__(256)
void k_agg_bf(const unsigned short* __restrict__ xw, const int* __restrict__ rowp,
              const int* __restrict__ csr, const float* __restrict__ dinv,
              const float* __restrict__ bias, unsigned short* __restrict__ out) {
    int w = threadIdx.x >> 6, lane = threadIdx.x & 63;
    int v = blockIdx.x * 4 + w;
    if (v >= Nn_) return;
    const uint2* x64 = (const uint2*)xw;
    uint2 us = x64[(size_t)v * 64 + lane];
    float dv = dinv[v];
    float4 bv = *(const float4*)(bias + lane * 4);
    float a0 = 0.f, a1 = 0.f, a2 = 0.f, a3 = 0.f;
    int beg = rowp[v], end = rowp[v + 1];
    uint2 u0 = make_uint2(0, 0), u1 = make_uint2(0, 0);
    uint2 u2 = make_uint2(0, 0), u3 = make_uint2(0, 0);
    float e0 = 0.f, e1 = 0.f, e2 = 0.f, e3 = 0.f;
    if (beg < end)     { int s = csr[beg];     e0 = dinv[s]; u0 = x64[(size_t)s * 64 + lane]; }
    if (beg + 1 < end) { int s = csr[beg + 1]; e1 = dinv[s]; u1 = x64[(size_t)s * 64 + lane]; }
    if (beg + 2 < end) { int s = csr[beg + 2]; e2 = dinv[s]; u2 = x64[(size_t)s * 64 + lane]; }
    if (beg + 3 < end) { int s = csr[beg + 3]; e3 = dinv[s]; u3 = x64[(size_t)s * 64 + lane]; }
    #pragma unroll 4
    for (int p = beg; p < end; ++p) {
        uint2 uc = u0; float dc = e0;
        u0 = u1; e0 = e1;
        u1 = u2; e1 = e2;
        u2 = u3; e2 = e3;
        if (p + 4 < end) {
            int s = csr[p + 4];
            e3 = dinv[s];
            u3 = x64[(size_t)s * 64 + lane];
        }
        a0 += bf2f(uc.x & 0xffff) * dc;
        a1 += bf2f(uc.x >> 16) * dc;
        a2 += bf2f(uc.y & 0xffff) * dc;
        a3 += bf2f(uc.y >> 16) * dc;
    }
    a0 = a0 * dv + bf2f(us.x & 0xffff) * dv * dv;
    a1 = a1 * dv + bf2f(us.x >> 16) * dv * dv;
    a2 = a2 * dv + bf2f(us.y & 0xffff) * dv * dv;
    a3 = a3 * dv + bf2f(us.y >> 16) * dv * dv;
    uint2 ov;
    ov.x = (unsigned int)f2bf(tanh_fast(a0 + bv.x)) |
           ((unsigned int)f2bf(tanh_fast(a1 + bv.y)) << 16);
    ov.y = (unsigned int)f2bf(tanh_fast(a2 + bv.z)) |
           ((unsigned int)f2bf(tanh_fast(a3 + bv.w)) << 16);
    ((uint2*)out)[(size_t)v * 64 + lane] = ov;
}

// ---------------- MFMA GEMM, dbuf LDS + raw barriers + counted vmcnt ----------------
template <bool BIAS, bool TANH>
__global__ __launch_bounds__(256)
void mfma_gemm(const unsigned short* __restrict__ A0, const unsigned short* __restrict__ A1,
               int Ksplit, int K, const unsigned short* __restrict__ Bt,
               const float* __restrict__ bias, unsigned short* __restrict__ Cb, int M) {
    __shared__ char lds[2][16384];
    int tid = threadIdx.x, lane = tid & 63, w = tid >> 6;
    int row0 = blockIdx.y * 128, col0 = blockIdx.x * 128;
    int wr = w >> 1, wc = w & 1;
    f32x4 acc[4][4] = {};
    int nk = K >> 5;

    auto stage = [&](int ks, int buf) {
        int k0 = ks << 5;
        #pragma unroll
        for (int j = 0; j < 4; ++j) {
            int ins = w + (j << 2);
            int lrow = ((ins & 7) << 4) + (lane >> 2);
            int p = lane & 3;
            int slog = p ^ ((lrow >> 1) & 3);
            char* ldst = lds[buf] + ((ins & 7) << 10) + ((ins >= 8) ? 8192 : 0);
            const unsigned short* src;
            if (ins < 8) {
                int grow = row0 + lrow;
                if (grow >= M) grow = M - 1;
                const unsigned short* Asrc; int kk, pitch;
                if (k0 < Ksplit) { Asrc = A0; kk = k0; pitch = Ksplit; }
                else             { Asrc = A1; kk = k0 - Ksplit; pitch = K - Ksplit; }
                src = Asrc + (size_t)grow * pitch + kk + (slog << 3);
            } else {
                int grow = col0 + lrow;
                src = Bt + (size_t)grow * K + k0 + (slog << 3);
            }
            gload_lds16(src, ldst);
        }
    };

    stage(0, 0);
    for (int ks = 0; ks < nk; ++ks) {
        int cur = ks & 1;
        if (ks + 1 < nk) {
            stage(ks + 1, cur ^ 1);
            asm volatile("s_waitcnt vmcnt(4)" ::: "memory");
        } else {
            asm volatile("s_waitcnt vmcnt(0)" ::: "memory");
        }
        __builtin_amdgcn_s_barrier();
        __builtin_amdgcn_sched_barrier(0);
        int s = lane >> 4, r16 = lane & 15;
        bf16x8 a[4], b[4];
        #pragma unroll
        for (int m = 0; m < 4; ++m) a[m] = *(const bf16x8*)(lds[cur] + lds_off(wr * 64 + m * 16 + r16, s));
        #pragma unroll
        for (int n = 0; n < 4; ++n) b[n] = *(const bf16x8*)(lds[cur] + 8192 + lds_off(wc * 64 + n * 16 + r16, s));
        __builtin_amdgcn_s_setprio(1);
        #pragma unroll
        for (int m = 0; m < 4; ++m)
            #pragma unroll
            for (int n = 0; n < 4; ++n)
                acc[m][n] = __builtin_amdgcn_mfma_f32_16x16x32_bf16(a[m], b[n], acc[m][n], 0, 0, 0);
        __builtin_amdgcn_s_setprio(0);
        __builtin_amdgcn_s_barrier();
        __builtin_amdgcn_sched_barrier(0);
    }
    int q = lane >> 4, r16 = lane & 15;
    float bv[4];
    #pragma unroll
    for (int n = 0; n < 4; ++n) bv[n] = BIAS ? bias[col0 + wc * 64 + n * 16 + r16] : 0.f;
    #pragma unroll
    for (int m = 0; m < 4; ++m) {
        #pragma unroll
        for (int i = 0; i < 4; ++i) {
            int row = row0 + wr * 64 + m * 16 + q * 4 + i;
            if (row >= M) continue;
            #pragma unroll
            for (int n = 0; n < 4; ++n) {
                int col = col0 + wc * 64 + n * 16 + r16;
                float v = acc[m][n][i];
                if (BIAS) v += bv[n];
                if (TANH) v = tanh_fast(v);
                Cb[(size_t)row * 256 + col] = f2bf(v);
            }
        }
    }
}

// ---------------- attention u: 16 lanes/node, online softmax ----------------
__global__ __launch_bounds__(256)
void k_attn_u2(const unsigned short* __restrict__ emb, const unsigned short* __restrict__ t,
               const float* __restrict__ p0, const float* __restrict__ p1,
               const float* __restrict__ p2, unsigned short* __restrict__ u) {
    int tid = threadIdx.x;
    int g = tid >> 4, l = tid & 15;
    int n = blockIdx.x * 16 + g;
    size_t eoff = (size_t)n * 256 + l * 16;
    const uint4* e16 = (const uint4*)(emb + eoff);
    uint4* u16 = (uint4*)(u + eoff);
    uint4 eb0 = e16[0], eb1 = e16[1];
    if (n >= P2_) { u16[0] = eb0; u16[1] = eb1; return; }
    float tv[16], ev[16];
    {
        const uint4* t16 = (const uint4*)(t + eoff);
        unpk8(t16[0], tv); unpk8(t16[1], tv + 8);
        unpk8(eb0, ev); unpk8(eb1, ev + 8);
    }
    float m = -3.0e38f, den = 0.f, o[16];
    #pragma unroll
    for (int i = 0; i < 16; i++) o[i] = 0.f;
    auto accum = [&](const float* sv) {
        float dt = 0.f;
        #pragma unroll
        for (int i = 0; i < 16; i++) dt += tv[i] * sv[i];
        dt += __shfl_xor(dt, 1);
        dt += __shfl_xor(dt, 2);
        dt += __shfl_xor(dt, 4);
        dt += __shfl_xor(dt, 8);
        float lg = dt * 0.0625f;
        float mn = fmaxf(m, lg);
        float s0 = __expf(m - mn), s1 = __expf(lg - mn);
        den = den * s0 + s1;
        #pragma unroll
        for (int i = 0; i < 16; i++) o[i] = o[i] * s0 + s1 * sv[i];
        m = mn;
    };
    auto accum_f32 = [&](const float* base) {
        float sv[16];
        const float4* b4 = (const float4*)(base + eoff);
        #pragma unroll
        for (int i = 0; i < 4; i++) {
            float4 q = b4[i];
            sv[4 * i] = q.x; sv[4 * i + 1] = q.y; sv[4 * i + 2] = q.z; sv[4 * i + 3] = q.w;
        }
        accum(sv);
    };
    if (n < P0_)      { accum_f32(p0); accum_f32(p1); accum_f32(p2); }
    else if (n < P1_) { accum_f32(p1); accum_f32(p2); }
    else              { accum_f32(p2); }
    accum(ev);
    float inv = __builtin_amdgcn_rcpf(den);
    unsigned short h[16];
    #pragma unroll
    for (int i = 0; i < 16; i++) h[i] = f2bf(o[i] * inv);
    uint4 r0, r1;
    r0.x = h[0] | ((unsigned int)h[1] << 16);  r0.y = h[2] | ((unsigned int)h[3] << 16);
    r0.z = h[4] | ((unsigned int)h[5] << 16);  r0.w = h[6] | ((unsigned int)h[7] << 16);
    r1.x = h[8] | ((unsigned int)h[9] << 16);  r1.y = h[10] | ((unsigned int)h[11] << 16);
    r1.z = h[12] | ((unsigned int)h[13] << 16); r1.w = h[14] | ((unsigned int)h[15] << 16);
    u16[0] = r0; u16[1] = r1;
}

// ---------------- fused edge MLP v7: grid-fused ml+ms tasks, dbuf A-tile, 1 barrier/step ----------------
__global__ __launch_bounds__(256)
void mfma_edge7(const unsigned short* __restrict__ emb2b, const unsigned short* __restrict__ rtabb,
                const unsigned short* __restrict__ gtab,
                const int* __restrict__ es, const int* __restrict__ ed,
                const unsigned short* __restrict__ PkMl, const unsigned short* __restrict__ PkMs,
                const float* __restrict__ b1ml, const float* __restrict__ w2ml,
                const float* __restrict__ b1ms, const float* __restrict__ w2ms,
                const float* __restrict__ sumb,
                float* __restrict__ apml, float* __restrict__ apms,
                float* __restrict__ mlsc, int nml) {
    __shared__ char lds[16384];   // dbuf: buf0 [mean 4K | max 4K], buf1 at 8192
    __shared__ float red[64];
    bool sim = (int)blockIdx.x < nml;
    int bid = sim ? blockIdx.x : (blockIdx.x - nml);
    const unsigned short* srcemb = sim ? emb2b : rtabb;
    const unsigned short* PkF = sim ? PkMl : PkMs;
    const float* b1 = sim ? b1ml : b1ms;
    const float* w2 = sim ? w2ml : w2ms;
    float* a_pre = sim ? apml : apms;
    int tid = threadIdx.x, lane = tid & 63, w = tid >> 6;
    int e0 = bid * 64;
    int arow = tid >> 2, p = tid & 3;
    int ia = es[e0 + arow], ib = ed[e0 + arow];
    const unsigned short* ra = srcemb + (size_t)ia * 256;
    const unsigned short* rb = srcemb + (size_t)ib * 256;
    const unsigned short* rg = gtab + (size_t)ia * 256;
    int slog = p ^ ((arow >> 1) & 3);
    int abase = arow * 64 + (p << 4);
    if (tid < 64) red[tid] = 0.f;
    float simacc = 0.f;
    f32x4 acc[4][4] = {};
    // prologue: prefetch step-0 A slices into registers
    uint4 pa = *(const uint4*)(ra + (slog << 3));
    uint4 pb = *(const uint4*)(rb + (slog << 3));
    uint4 pg = make_uint4(0, 0, 0, 0);
    if (sim) pg = *(const uint4*)(rg + (slog << 3));
    const bf16x8* BF = (const bf16x8*)PkF;
    for (int os = 0; os < 8; ++os) {
        int cbuf = (os & 1) << 13;      // 0 or 8192
        // A convert + swizzled ds_write into current buffer
        {
            unsigned int m0, x0, m1, x1, m2, x2, m3, x3;
            meanmax_u(pa.x, pb.x, m0, x0);
            meanmax_u(pa.y, pb.y, m1, x1);
            meanmax_u(pa.z, pb.z, m2, x2);
            meanmax_u(pa.w, pb.w, m3, x3);
            *(uint4*)(lds + cbuf + abase) = make_uint4(m0, m1, m2, m3);
            *(uint4*)(lds + cbuf + 4096 + abase) = make_uint4(x0, x1, x2, x3);
            if (sim)
                simacc += dot2_u(pg.x, pb.x) + dot2_u(pg.y, pb.y) +
                          dot2_u(pg.z, pb.z) + dot2_u(pg.w, pb.w);
        }
        // B-frag loads BEFORE A-prefetch (vmcnt FIFO: prefetch stays newest, never drained early)
        bf16x8 b0[4], b1f[4];
        #pragma unroll
        for (int n2 = 0; n2 < 4; ++n2) {
            int c0i = (os << 5) + (w << 2) + n2;
            b0[n2]  = BF[(size_t)c0i * 64 + lane];
            b1f[n2] = BF[(size_t)(c0i + 16) * 64 + lane];
        }
        // A-gather prefetch for step os+1
        if (os < 7) {
            int cb = ((os + 1) << 5) + (slog << 3);
            pa = *(const uint4*)(ra + cb);
            pb = *(const uint4*)(rb + cb);
            if (sim) pg = *(const uint4*)(rg + cb);
        }
        // single barrier per step: lgkm drains this step's ds_writes AND prior ds_reads,
        // so buffer reuse at os+2 is race-free (all waves passed barrier os+1 with reads done)
        asm volatile("s_waitcnt lgkmcnt(0)" ::: "memory");
        __builtin_amdgcn_s_barrier();
        __builtin_amdgcn_sched_barrier(0);
        int s = lane >> 4, r16 = lane & 15;
        {
            bf16x8 a[4];
            #pragma unroll
            for (int m2 = 0; m2 < 4; ++m2)
                a[m2] = *(const bf16x8*)(lds + cbuf + lds_off(m2 * 16 + r16, s));
            __builtin_amdgcn_s_setprio(1);
            #pragma unroll
            for (int m2 = 0; m2 < 4; ++m2)
                #pragma unroll
                for (int n2 = 0; n2 < 4; ++n2)
                    acc[m2][n2] = __builtin_amdgcn_mfma_f32_16x16x32_bf16(a[m2], b0[n2], acc[m2][n2], 0, 0, 0);
            __builtin_amdgcn_s_setprio(0);
        }
        {
            bf16x8 a[4];
            #pragma unroll
            for (int m2 = 0; m2 < 4; ++m2)
                a[m2] = *(const bf16x8*)(lds + cbuf + 4096 + lds_off(m2 * 16 + r16, s));
            __builtin_amdgcn_s_setprio(1);
            #pragma unroll
            for (int m2 = 0; m2 < 4; ++m2)
                #pragma unroll
                for (int n2 = 0; n2 < 4; ++n2)
                    acc[m2][n2] = __builtin_amdgcn_mfma_f32_16x16x32_bf16(a[m2], b1f[n2], acc[m2][n2], 0, 0, 0);
            __builtin_amdgcn_s_setprio(0);
        }
        // no trailing barrier: next step writes the other buffer
    }
    // epilogue: layer-2 dot, reduce to per-edge scalar
    int q = lane >> 4, r16 = lane & 15;
    float b1c[4], w2c[4];
    #pragma unroll
    for (int n2 = 0; n2 < 4; ++n2) {
        int c = (w << 6) + n2 * 16 + r16;
        b1c[n2] = b1[c]; w2c[n2] = w2[c];
    }
    #pragma unroll
    for (int m2 = 0; m2 < 4; ++m2) {
        #pragma unroll
        for (int i = 0; i < 4; ++i) {
            int row = m2 * 16 + q * 4 + i;
            float ps = 0.f;
            #pragma unroll
            for (int n2 = 0; n2 < 4; ++n2) ps += tanh_fast(acc[m2][n2][i] + b1c[n2]) * w2c[n2];
            ps += __shfl_xor(ps, 1);
            ps += __shfl_xor(ps, 2);
            ps += __shfl_xor(ps, 4);
            ps += __shfl_xor(ps, 8);
            if (r16 == 0) atomicAdd(&red[row], ps);
        }
    }
    if (sim) {
        simacc += __shfl_xor(simacc, 1);
        simacc += __shfl_xor(simacc, 2);
        if (p == 0) mlsc[e0 + arow] = sigmoid_fast(simacc + sumb[0]);
    }
    __syncthreads();
    if (tid < 64) a_pre[e0 + tid] = red[tid];
}

// ---------------- final ensemble ----------------
__global__ void k_final(const float* __restrict__ apml, const float* __restrict__ apms,
                        const float* __restrict__ mlsc, const float* __restrict__ mstr,
                        const float* __restrict__ pxtr, const int* __restrict__ index,
                        const float* __restrict__ mlb2, const float* __restrict__ msb2,
                        float* __restrict__ out) {
    int e = blockIdx.x * 256 + threadIdx.x;
    if (e >= E_) return;
    float aml = tanh_fast(apml[e] + mlb2[0]);
    float ams = tanh_fast(apms[e] + msb2[0]);
    float apx = PROXW;
    float m = fmaxf(aml, fmaxf(ams, apx));
    float wml = __expf(aml - m), wms = __expf(ams - m), wpx = __expf(apx - m);
    float inv = __builtin_amdgcn_rcpf(wml + wms + wpx);
    int idx = index[e];
    float v = (mlsc[e] * wml + mstr[idx] * wms + pxtr[idx] * wpx) * inv;
    out[e] = fminf(fmaxf(v, 0.f), 1.f);
}

__global__ void k_sentinel(float* out, int n) {
    int i = blockIdx.x * 256 + threadIdx.x;
    if (i < n) out[i] = -12345.0f;
}

// ---------------- launch ----------------
extern "C" void kernel_launch(void* const* d_in, const int* in_sizes, int n_in,
                              void* d_out, int out_size, void* d_ws, size_t ws_size,
                              hipStream_t stream) {
    const float* x     = (const float*)d_in[0];
    const int*   mp    = (const int*)d_in[1];
    const int*   edges = (const int*)d_in[2];
    const int*   index = (const int*)d_in[3];
    const float* p0    = (const float*)d_in[4];
    const float* p1    = (const float*)d_in[5];
    const float* p2    = (const float*)d_in[6];
    const float* gc1W  = (const float*)d_in[7];
    const float* gc1b  = (const float*)d_in[8];
    const float* gc2W  = (const float*)d_in[9];
    const float* gc2b  = (const float*)d_in[10];
    const float* linW  = (const float*)d_in[11];
    const float* linb  = (const float*)d_in[12];
    const float* wlin  = (const float*)d_in[13];
    const float* blin  = (const float*)d_in[14];
    const float* wq    = (const float*)d_in[15];
    const float* wk    = (const float*)d_in[16];
    const float* wv    = (const float*)d_in[17];
    const float* mlw1  = (const float*)d_in[18];
    const float* mlb1  = (const float*)d_in[19];
    const float* mlw2  = (const float*)d_in[20];
    const float* mlb2  = (const float*)d_in[21];
    const float* msw1  = (const float*)d_in[22];
    const float* msb1  = (const float*)d_in[23];
    const float* msw2  = (const float*)d_in[24];
    const float* msb2  = (const float*)d_in[25];
    const float* msdrW = (const float*)d_in[26];
    const float* msdrb = (const float*)d_in[27];
    const float* logits = (const float*)d_in[28];
    const float* mstr  = (const float*)d_in[29];
    const float* pxtr  = (const float*)d_in[30];
    float* out = (float*)d_out;

    const int* src_mp = mp;
    const int* dst_mp = mp + EMP_;
    const int* es = edges;
    const int* ed = edges + E_;

    char* ws = (char*)d_ws;
    size_t off = 0;
    auto alloc = [&](size_t bytes) -> char* {
        off = (off + 255) & ~(size_t)255;
        char* r = ws + off;
        off += bytes;
        return r;
    };
    const size_t NODE_BF = (size_t)Nn_ * 256 * 2;
    unsigned short* W0 = (unsigned short*)alloc(NODE_BF);  // xb -> gb
    unsigned short* W1 = (unsigned short*)alloc(NODE_BF);  // xw1/xw2 -> logitsb
    unsigned short* W2 = (unsigned short*)alloc(NODE_BF);  // hb -> rb
    unsigned short* W3 = (unsigned short*)alloc(NODE_BF);  // embb
    unsigned short* W4 = (unsigned short*)alloc(NODE_BF);  // tb/ub
    unsigned short* W5 = (unsigned short*)alloc(NODE_BF);  // emb2b
    int*   cnt  = (int*)alloc((size_t)Nn_ * 4);
    int*   rowp = (int*)alloc((size_t)(Nn_ + 1) * 4);
    int*   fill = (int*)alloc((size_t)Nn_ * 4);
    int*   csr  = (int*)alloc((size_t)EMP_ * 4);
    float* dinv = (float*)alloc((size_t)Nn_ * 4);
    int*   bsum = (int*)alloc(512 * 4);
    float* Mqk  = (float*)alloc(65536 * 4);
    float* W2wf = (float*)alloc(65536 * 4);
    unsigned short* gc1Wt = (unsigned short*)alloc(65536 * 2);
    unsigned short* gc2Wt = (unsigned short*)alloc(65536 * 2);
    unsigned short* MqkT  = (unsigned short*)alloc(65536 * 2);
    unsigned short* Bt512 = (unsigned short*)alloc(131072 * 2);
    unsigned short* symb  = (unsigned short*)alloc(65536 * 2);
    unsigned short* msdrWt = (unsigned short*)alloc(16384 * 2);
    unsigned short* mlPk  = (unsigned short*)alloc(131072 * 2);
    unsigned short* msPk  = (unsigned short*)alloc(131072 * 2);
    float* apml = (float*)alloc((size_t)E_ * 4);
    float* apms = (float*)alloc((size_t)E_ * 4);
    float* mlsc = (float*)alloc((size_t)E_ * 4);
    float* sumb = (float*)alloc(256);

    if (off > ws_size) {
        k_sentinel<<<(E_ + 255) / 256, 256, 0, stream>>>(out, E_);
        return;
    }

    hipMemsetAsync(cnt, 0, (size_t)Nn_ * 4, stream);
    hipMemsetAsync(fill, 0, (size_t)Nn_ * 4, stream);

    const int NB = (Nn_ + 255) / 256;
    const int EB = (EMP_ + 255) / 256;

    // input conversions + consolidated weight prep
    k_cvt<<<30000, 256, 0, stream>>>(x, W0, Nn_ * 256 / 4);
    k_prep1<<<1153, 256, 0, stream>>>(gc1W, gc2W, msdrW, wlin, blin, mlw1, msw1,
                                      gc1Wt, gc2Wt, msdrWt, symb, sumb, mlPk, msPk);
    dim3 gSmall(4, 4);
    gemm_tiled<true><<<gSmall, 256, 0, stream>>>(wq, wk, Mqk, 256, 256, 256);
    gemm_tiled<false><<<gSmall, 256, 0, stream>>>(wv, linW + 256 * 256, W2wf, 256, 256, 256);
    k_prep2<<<768, 256, 0, stream>>>(Mqk, linW, W2wf, MqkT, Bt512);

    // CSR
    k_count<<<EB, 256, 0, stream>>>(dst_mp, cnt, EMP_);
    k_block_reduce<<<NB, 256, 0, stream>>>(cnt, bsum, Nn_);
    k_scan_bsum<<<1, 64, 0, stream>>>(bsum, NB);
    k_scan_final<<<NB, 256, 0, stream>>>(cnt, bsum, rowp, Nn_, EMP_);
    k_fill<<<EB, 256, 0, stream>>>(src_mp, dst_mp, rowp, fill, csr, EMP_);
    k_dinv<<<NB, 256, 0, stream>>>(cnt, dinv, Nn_);

    dim3 gFull(2, (Nn_ + 127) / 128);
    dim3 gT(2, (P2_ + 127) / 128);
    const int AGG_B = (Nn_ + 3) / 4;

    // GCN layer 1
    mfma_gemm<false, false><<<gFull, 256, 0, stream>>>(W0, W0, 256, 256, gc1Wt, nullptr, W1, Nn_);
    k_agg_bf<<<AGG_B, 256, 0, stream>>>(W1, rowp, csr, dinv, gc1b, W2);
    // GCN layer 2
    mfma_gemm<false, false><<<gFull, 256, 0, stream>>>(W2, W2, 256, 256, gc2Wt, nullptr, W1, Nn_);
    k_agg_bf<<<AGG_B, 256, 0, stream>>>(W1, rowp, csr, dinv, gc2b, W3);

    // attention: t = emb @ Mqk (rows < P2), then u (16 nodes/block)
    mfma_gemm<false, false><<<gT, 256, 0, stream>>>(W3, W3, 256, 256, MqkT, nullptr, W4, P2_);
    k_attn_u2<<<Nn_ / 16, 256, 0, stream>>>(W3, W4, p0, p1, p2, W4);

    // emb2 = tanh([emb|u] @ Bt512^T + linb)
    mfma_gemm<true, true><<<gFull, 256, 0, stream>>>(W3, W4, 256, 512, Bt512, linb, W5, Nn_);

    // g = emb2 @ sym
    mfma_gemm<false, false><<<gFull, 256, 0, stream>>>(W5, W5, 256, 256, symb, nullptr, W0, Nn_);

    // r = tanh(logits @ msdrW + msdrb)
    k_cvt<<<7500, 256, 0, stream>>>(logits, W1, Nn_ * 64 / 4);
    mfma_gemm<true, true><<<gFull, 256, 0, stream>>>(W1, W1, 64, 64, msdrWt, msdrb, W2, Nn_);

    // grid-fused edge MLPs (+fused bilinear sim in ml blocks)
    const int NML = E_ / 64;   // 3125
    mfma_edge7<<<2 * NML, 256, 0, stream>>>(W5, W2, W0, es, ed, mlPk, msPk,
                                            mlb1, mlw2, msb1, msw2, sumb,
                                            apml, apms, mlsc, NML);

    // final ensemble
    k_final<<<(E_ + 255) / 256, 256, 0, stream>>>(apml, apms, mlsc, mstr, pxtr, index, mlb2, msb2, out);
}